// Round 1
// baseline (1096.408 us; speedup 1.0000x reference)
//
#include <hip/hip_runtime.h>

#define NB 16384
#define NDOM 10
#define HIDN 512
#define STYLE 64

constexpr int BM = 128;
constexpr int BK = 16;

// ---------------- domain bucketing ----------------

__global__ void k_init(int* counts, int* cursors) {
    int t = threadIdx.x;
    if (t < NDOM) { counts[t] = 0; cursors[t] = 0; }
}

__global__ void k_hist(const int* __restrict__ y, int* __restrict__ counts) {
    int b = blockIdx.x * 256 + threadIdx.x;
    int d = (b < NB) ? y[b] : -1;
    int lane = threadIdx.x & 63;
#pragma unroll
    for (int dd = 0; dd < NDOM; ++dd) {
        unsigned long long bal = __ballot(d == dd);
        if (bal == 0ULL) continue;
        int leader = __builtin_ctzll(bal);
        if (d == dd && lane == leader)
            atomicAdd(&counts[dd], (int)__popcll(bal));
    }
}

__global__ void k_scan(const int* __restrict__ counts, int* __restrict__ offsets) {
    if (threadIdx.x == 0) {
        int s = 0;
        for (int d = 0; d < NDOM; ++d) { offsets[d] = s; s += counts[d]; }
        offsets[NDOM] = s;
    }
}

__global__ void k_scatter(const int* __restrict__ y, const int* __restrict__ offsets,
                          int* __restrict__ cursors, int* __restrict__ rowidx) {
    int b = blockIdx.x * 256 + threadIdx.x;
    int d = (b < NB) ? y[b] : -1;
    int lane = threadIdx.x & 63;
#pragma unroll
    for (int dd = 0; dd < NDOM; ++dd) {
        unsigned long long bal = __ballot(d == dd);
        if (bal == 0ULL) continue;
        int leader = __builtin_ctzll(bal);
        int base = 0;
        if (d == dd && lane == leader)
            base = atomicAdd(&cursors[dd], (int)__popcll(bal));
        base = __shfl(base, leader);
        if (d == dd) {
            int rank = (int)__popcll(bal & ((1ULL << lane) - 1ULL));
            rowidx[offsets[dd] + base + rank] = b;
        }
    }
}

// ---------------- tiled fp32 GEMM: C = act(A @ W + b) ----------------
// BM=128 rows x BN=16*TN cols per block, 256 threads, 8 x TN per thread.
// dom_off == nullptr -> trunk mode over all NB rows.
// dom_off != nullptr -> head mode: blockIdx.y = domain, rows [off[d], off[d+1]).
// GATHER: input row g fetched from rowidx (original-order A, sorted output).
// SCATTER: output row written to rowidx position (sorted A, original-order C).

template<int TN, bool RELU, bool GATHER, bool SCATTER>
__global__ __launch_bounds__(256)
void k_gemm(const float* __restrict__ A, const float* __restrict__ Wb,
            const float* __restrict__ bb, float* __restrict__ C,
            const int K, const int N,
            const int* __restrict__ dom_off,
            const int* __restrict__ rowidx,
            const int wStride, const int bStride)
{
    constexpr int BN = 16 * TN;
    constexpr int WLD = (BN + 63) / 64;   // float4 W loads per thread per k-tile
    __shared__ float As[BK][BM + 4];      // transposed: As[k][m], padded, 16B-aligned rows
    __shared__ float Ws[BK][BN + 4];

    int sortBase, Md;
    const float *W, *bias;
    if (dom_off) {
        const int dom = blockIdx.y;
        sortBase = dom_off[dom];
        Md = dom_off[dom + 1] - sortBase;
        W = Wb + (size_t)dom * wStride;
        bias = bb + (size_t)dom * bStride;
    } else {
        sortBase = 0; Md = NB; W = Wb; bias = bb;
    }
    const int tiles_n = N / BN;
    const int tm = (int)blockIdx.x / tiles_n;
    const int tn = (int)blockIdx.x % tiles_n;
    const int m0 = tm * BM;
    if (m0 >= Md) return;          // inactive tile (head mode worst-case grid)
    const int n0 = tn * BN;

    const int tid = threadIdx.x;
    const int tx = tid & 15;
    const int ty = tid >> 4;

    // staging maps
    const int aRow = tid >> 1;            // 0..127
    const int aK = (tid & 1) * 8;         // 0 or 8
    const int wRow = tid >> 4;            // 0..15
    const int wCol = (tid & 15) * 4;      // 0..60

    const bool aValid = (m0 + aRow) < Md;
    const float* Aptr = A;
    if (aValid) {
        int g = m0 + aRow;
        int src = GATHER ? rowidx[sortBase + g] : (dom_off ? sortBase + g : g);
        Aptr = A + (size_t)src * K + aK;
    }
    const float* wBase = W + (size_t)wRow * N + n0 + wCol;

    float acc[8][TN];
#pragma unroll
    for (int i = 0; i < 8; ++i)
#pragma unroll
        for (int j = 0; j < TN; ++j) acc[i][j] = 0.f;

    float4 a0, a1, wr[WLD];
    auto ldTile = [&](int kt) {
        const int kk = kt * BK;
        if (aValid) {
            a0 = *(const float4*)(Aptr + kk);
            a1 = *(const float4*)(Aptr + kk + 4);
        } else {
            a0 = make_float4(0.f, 0.f, 0.f, 0.f);
            a1 = a0;
        }
#pragma unroll
        for (int l = 0; l < WLD; ++l)
            wr[l] = *(const float4*)(wBase + (size_t)kk * N + l * 64);
    };

    ldTile(0);
    const int nkt = K / BK;
    for (int kt = 0; kt < nkt; ++kt) {
        if (kt) __syncthreads();
        // staged regs -> LDS (A transposed)
        As[aK + 0][aRow] = a0.x; As[aK + 1][aRow] = a0.y;
        As[aK + 2][aRow] = a0.z; As[aK + 3][aRow] = a0.w;
        As[aK + 4][aRow] = a1.x; As[aK + 5][aRow] = a1.y;
        As[aK + 6][aRow] = a1.z; As[aK + 7][aRow] = a1.w;
#pragma unroll
        for (int l = 0; l < WLD; ++l)
            *(float4*)&Ws[wRow][wCol + l * 64] = wr[l];
        __syncthreads();
        if (kt + 1 < nkt) ldTile(kt + 1);   // next tile in flight during compute
#pragma unroll
        for (int k = 0; k < BK; ++k) {
            const float4 x0 = *(const float4*)&As[k][ty * 8];
            const float4 x1 = *(const float4*)&As[k][ty * 8 + 4];
            float av[8] = {x0.x, x0.y, x0.z, x0.w, x1.x, x1.y, x1.z, x1.w};
            float wv[TN];
#pragma unroll
            for (int j4 = 0; j4 < TN / 4; ++j4) {
                const float4 t = *(const float4*)&Ws[k][tx * TN + j4 * 4];
                wv[j4 * 4 + 0] = t.x; wv[j4 * 4 + 1] = t.y;
                wv[j4 * 4 + 2] = t.z; wv[j4 * 4 + 3] = t.w;
            }
#pragma unroll
            for (int i = 0; i < 8; ++i)
#pragma unroll
                for (int j = 0; j < TN; ++j)
                    acc[i][j] = fmaf(av[i], wv[j], acc[i][j]);
        }
    }

    // epilogue: bias + relu + store
    float bv[TN];
#pragma unroll
    for (int j = 0; j < TN; ++j) bv[j] = bias[n0 + tx * TN + j];
#pragma unroll
    for (int i = 0; i < 8; ++i) {
        const int g = m0 + ty * 8 + i;
        if (g < Md) {
            int orow = SCATTER ? rowidx[sortBase + g] : (dom_off ? sortBase + g : g);
            float* cp = C + (size_t)orow * N + n0 + tx * TN;
#pragma unroll
            for (int j4 = 0; j4 < TN / 4; ++j4) {
                float4 v;
                v.x = acc[i][j4 * 4 + 0] + bv[j4 * 4 + 0];
                v.y = acc[i][j4 * 4 + 1] + bv[j4 * 4 + 1];
                v.z = acc[i][j4 * 4 + 2] + bv[j4 * 4 + 2];
                v.w = acc[i][j4 * 4 + 3] + bv[j4 * 4 + 3];
                if (RELU) {
                    v.x = fmaxf(v.x, 0.f); v.y = fmaxf(v.y, 0.f);
                    v.z = fmaxf(v.z, 0.f); v.w = fmaxf(v.w, 0.f);
                }
                *(float4*)(cp + j4 * 4) = v;
            }
        }
    }
}

// ---------------- launch ----------------

extern "C" void kernel_launch(void* const* d_in, const int* in_sizes, int n_in,
                              void* d_out, int out_size, void* d_ws, size_t ws_size,
                              hipStream_t stream) {
    const float* z   = (const float*)d_in[0];
    const int*   y   = (const int*)d_in[1];
    const float* W0  = (const float*)d_in[2];
    const float* b0  = (const float*)d_in[3];
    const float* W1  = (const float*)d_in[4];
    const float* b1  = (const float*)d_in[5];
    const float* W2  = (const float*)d_in[6];
    const float* b2  = (const float*)d_in[7];
    const float* W3  = (const float*)d_in[8];
    const float* b3  = (const float*)d_in[9];
    const float* Wu1 = (const float*)d_in[10];
    const float* bu1 = (const float*)d_in[11];
    const float* Wu2 = (const float*)d_in[12];
    const float* bu2 = (const float*)d_in[13];
    const float* Wu3 = (const float*)d_in[14];
    const float* bu3 = (const float*)d_in[15];
    const float* Wo  = (const float*)d_in[16];
    const float* bo  = (const float*)d_in[17];
    float* out = (float*)d_out;

    char* ws = (char*)d_ws;
    float* bufA = (float*)ws;                                  // NB*512 f32
    float* bufB = (float*)(ws + (size_t)NB * HIDN * 4);        // NB*512 f32
    int* rowidx  = (int*)(ws + (size_t)2 * NB * HIDN * 4);     // NB ints
    int* counts  = rowidx + NB;
    int* cursors = counts + NDOM;
    int* offsets = cursors + NDOM;                             // NDOM+1 ints

    // domain bucketing
    k_init<<<1, 64, 0, stream>>>(counts, cursors);
    k_hist<<<NB / 256, 256, 0, stream>>>(y, counts);
    k_scan<<<1, 64, 0, stream>>>(counts, offsets);
    k_scatter<<<NB / 256, 256, 0, stream>>>(y, offsets, cursors, rowidx);

    const dim3 blk(256);
    const dim3 gT((NB / BM) * (HIDN / 128));          // trunk: 512 blocks
    const dim3 gH((NB / BM) * (HIDN / 128), NDOM);    // heads: worst-case grid
    const dim3 gO((NB / BM) * (STYLE / 64), NDOM);    // final 512->64

    // trunk (original row order)
    k_gemm<8, true, false, false><<<gT, blk, 0, stream>>>(z,    W0, b0, bufA, 16,   HIDN, nullptr, nullptr, 0, 0);
    k_gemm<8, true, false, false><<<gT, blk, 0, stream>>>(bufA, W1, b1, bufB, HIDN, HIDN, nullptr, nullptr, 0, 0);
    k_gemm<8, true, false, false><<<gT, blk, 0, stream>>>(bufB, W2, b2, bufA, HIDN, HIDN, nullptr, nullptr, 0, 0);
    k_gemm<8, true, false, false><<<gT, blk, 0, stream>>>(bufA, W3, b3, bufB, HIDN, HIDN, nullptr, nullptr, 0, 0);
    // heads: only the selected domain per row (sorted order)
    k_gemm<8, true, true,  false><<<gH, blk, 0, stream>>>(bufB, Wu1, bu1, bufA, HIDN, HIDN, offsets, rowidx, HIDN * HIDN, HIDN);
    k_gemm<8, true, false, false><<<gH, blk, 0, stream>>>(bufA, Wu2, bu2, bufB, HIDN, HIDN, offsets, rowidx, HIDN * HIDN, HIDN);
    k_gemm<8, true, false, false><<<gH, blk, 0, stream>>>(bufB, Wu3, bu3, bufA, HIDN, HIDN, offsets, rowidx, HIDN * HIDN, HIDN);
    k_gemm<4, false, false, true><<<gO, blk, 0, stream>>>(bufA, Wo,  bo,  out,  HIDN, STYLE, offsets, rowidx, HIDN * STYLE, STYLE);
}

// Round 2
// 510.968 us; speedup vs baseline: 2.1457x; 2.1457x over previous
//
#include <hip/hip_runtime.h>

#define NB 16384
#define NDOM 10
#define HIDN 512
#define STYLE 64

typedef short bf16x8 __attribute__((ext_vector_type(8)));
typedef float f32x16 __attribute__((ext_vector_type(16)));

// ---------------- domain bucketing ----------------

__global__ void k_init(int* counts, int* cursors) {
    int t = threadIdx.x;
    if (t < NDOM) { counts[t] = 0; cursors[t] = 0; }
}

__global__ void k_hist(const int* __restrict__ y, int* __restrict__ counts) {
    int b = blockIdx.x * 256 + threadIdx.x;
    int d = (b < NB) ? y[b] : -1;
    int lane = threadIdx.x & 63;
#pragma unroll
    for (int dd = 0; dd < NDOM; ++dd) {
        unsigned long long bal = __ballot(d == dd);
        if (bal == 0ULL) continue;
        int leader = __builtin_ctzll(bal);
        if (d == dd && lane == leader)
            atomicAdd(&counts[dd], (int)__popcll(bal));
    }
}

__global__ void k_scan(const int* __restrict__ counts, int* __restrict__ offsets) {
    if (threadIdx.x == 0) {
        int s = 0;
        for (int d = 0; d < NDOM; ++d) { offsets[d] = s; s += counts[d]; }
        offsets[NDOM] = s;
    }
}

__global__ void k_scatter(const int* __restrict__ y, const int* __restrict__ offsets,
                          int* __restrict__ cursors, int* __restrict__ rowidx) {
    int b = blockIdx.x * 256 + threadIdx.x;
    int d = (b < NB) ? y[b] : -1;
    int lane = threadIdx.x & 63;
#pragma unroll
    for (int dd = 0; dd < NDOM; ++dd) {
        unsigned long long bal = __ballot(d == dd);
        if (bal == 0ULL) continue;
        int leader = __builtin_ctzll(bal);
        int base = 0;
        if (d == dd && lane == leader)
            base = atomicAdd(&cursors[dd], (int)__popcll(bal));
        base = __shfl(base, leader);
        if (d == dd) {
            int rank = (int)__popcll(bal & ((1ULL << lane) - 1ULL));
            rowidx[offsets[dd] + base + rank] = b;
        }
    }
}

// ---------------- bf16 hi/lo split helpers ----------------

__device__ inline unsigned bfr_hi(float x) {
    unsigned u = __float_as_uint(x);
    return (u + 0x7fffu + ((u >> 16) & 1u)) & 0xffff0000u;  // RNE bf16 kept in high bits
}

// ---------------- weight prep: transpose + split into frag-linear chunks ----
// dst chunk (per mat, kt, ntile): el = (nf*4 + k8)*256 + col*8, 16B per (col,k8) octet.
// mats 0..2 = W1..W3 ; 3..12 = Wu1[d] ; 13..22 = Wu2[d] ; 23..32 = Wu3[d]

__global__ void k_prepw512(const float* __restrict__ W1, const float* __restrict__ W2,
                           const float* __restrict__ W3, const float* __restrict__ Wu1,
                           const float* __restrict__ Wu2, const float* __restrict__ Wu3,
                           short* __restrict__ WH, short* __restrict__ WL)
{
    const int mat = blockIdx.y;
    const int kt = blockIdx.x >> 2, tn = blockIdx.x & 3;
    const float* src;
    if (mat < 3) src = (mat == 0 ? W1 : (mat == 1 ? W2 : W3));
    else {
        int g = (mat - 3) / 10, d = (mat - 3) % 10;
        src = (g == 0 ? Wu1 : (g == 1 ? Wu2 : Wu3)) + (size_t)d * HIDN * HIDN;
    }
    short* dh = WH + ((size_t)(mat * 16 + kt) * 4 + tn) * 4096;
    short* dl = WL + ((size_t)(mat * 16 + kt) * 4 + tn) * 4096;
#pragma unroll
    for (int it = 0; it < 2; ++it) {
        int idx = it * 256 + threadIdx.x;
        int nl = idx & 127, k8 = idx >> 7;
        int n = tn * 128 + nl, k0 = kt * 32 + k8 * 8;
        unsigned hd[4], ld[4];
#pragma unroll
        for (int j2 = 0; j2 < 4; ++j2) {
            float x0 = src[(size_t)(k0 + j2 * 2) * HIDN + n];
            float x1 = src[(size_t)(k0 + j2 * 2 + 1) * HIDN + n];
            unsigned h0 = bfr_hi(x0), h1 = bfr_hi(x1);
            unsigned l0 = bfr_hi(x0 - __uint_as_float(h0));
            unsigned l1 = bfr_hi(x1 - __uint_as_float(h1));
            hd[j2] = (h0 >> 16) | (h1 & 0xffff0000u);
            ld[j2] = (l0 >> 16) | (l1 & 0xffff0000u);
        }
        int el = ((nl >> 5) * 4 + k8) * 256 + (nl & 31) * 8;
        *(uint4*)(dh + el) = make_uint4(hd[0], hd[1], hd[2], hd[3]);
        *(uint4*)(dl + el) = make_uint4(ld[0], ld[1], ld[2], ld[3]);
    }
}

__global__ void k_prepwo(const float* __restrict__ Wo,
                         short* __restrict__ WH, short* __restrict__ WL)
{
    const int mat = blockIdx.y;     // domain
    const int kt = blockIdx.x;      // 0..15
    const float* src = Wo + (size_t)mat * HIDN * STYLE;
    short* dh = WH + (size_t)(mat * 16 + kt) * 2048;
    short* dl = WL + (size_t)(mat * 16 + kt) * 2048;
    int idx = threadIdx.x;
    int nl = idx & 63, k8 = idx >> 6;
    int k0 = kt * 32 + k8 * 8;
    unsigned hd[4], ld[4];
#pragma unroll
    for (int j2 = 0; j2 < 4; ++j2) {
        float x0 = src[(size_t)(k0 + j2 * 2) * STYLE + nl];
        float x1 = src[(size_t)(k0 + j2 * 2 + 1) * STYLE + nl];
        unsigned h0 = bfr_hi(x0), h1 = bfr_hi(x1);
        unsigned l0 = bfr_hi(x0 - __uint_as_float(h0));
        unsigned l1 = bfr_hi(x1 - __uint_as_float(h1));
        hd[j2] = (h0 >> 16) | (h1 & 0xffff0000u);
        ld[j2] = (l0 >> 16) | (l1 & 0xffff0000u);
    }
    int el = ((nl >> 5) * 4 + k8) * 256 + (nl & 31) * 8;
    *(uint4*)(dh + el) = make_uint4(hd[0], hd[1], hd[2], hd[3]);
    *(uint4*)(dl + el) = make_uint4(ld[0], ld[1], ld[2], ld[3]);
}

// ---------------- layer-0 fp32 GEMM (K=16), trunk only ----------------

__global__ __launch_bounds__(256)
void k_gemm0(const float* __restrict__ A, const float* __restrict__ W,
             const float* __restrict__ bias, float* __restrict__ C)
{
    constexpr int BK = 16, BN = 128;
    __shared__ float As[BK][128 + 4];
    __shared__ float Ws[BK][BN + 4];
    const int tm = (int)blockIdx.x / 4, tn = (int)blockIdx.x % 4;
    const int m0 = tm * 128, n0 = tn * BN;
    const int tid = threadIdx.x;
    const int tx = tid & 15, ty = tid >> 4;
    const int aRow = tid >> 1, aK = (tid & 1) * 8;
    const int wRow = tid >> 4, wCol = (tid & 15) * 4;

    float4 a0 = *(const float4*)(A + (size_t)(m0 + aRow) * 16 + aK);
    float4 a1 = *(const float4*)(A + (size_t)(m0 + aRow) * 16 + aK + 4);
    float4 w0 = *(const float4*)(W + (size_t)wRow * HIDN + n0 + wCol);
    float4 w1 = *(const float4*)(W + (size_t)wRow * HIDN + n0 + wCol + 64);

    As[aK + 0][aRow] = a0.x; As[aK + 1][aRow] = a0.y;
    As[aK + 2][aRow] = a0.z; As[aK + 3][aRow] = a0.w;
    As[aK + 4][aRow] = a1.x; As[aK + 5][aRow] = a1.y;
    As[aK + 6][aRow] = a1.z; As[aK + 7][aRow] = a1.w;
    *(float4*)&Ws[wRow][wCol] = w0;
    *(float4*)&Ws[wRow][wCol + 64] = w1;
    __syncthreads();

    float acc[8][8];
#pragma unroll
    for (int i = 0; i < 8; ++i)
#pragma unroll
        for (int j = 0; j < 8; ++j) acc[i][j] = 0.f;
#pragma unroll
    for (int k = 0; k < BK; ++k) {
        const float4 x0 = *(const float4*)&As[k][ty * 8];
        const float4 x1 = *(const float4*)&As[k][ty * 8 + 4];
        float av[8] = {x0.x, x0.y, x0.z, x0.w, x1.x, x1.y, x1.z, x1.w};
        const float4 t0 = *(const float4*)&Ws[k][tx * 8];
        const float4 t1 = *(const float4*)&Ws[k][tx * 8 + 4];
        float wv[8] = {t0.x, t0.y, t0.z, t0.w, t1.x, t1.y, t1.z, t1.w};
#pragma unroll
        for (int i = 0; i < 8; ++i)
#pragma unroll
            for (int j = 0; j < 8; ++j)
                acc[i][j] = fmaf(av[i], wv[j], acc[i][j]);
    }
    float bv[8];
#pragma unroll
    for (int j = 0; j < 8; ++j) bv[j] = bias[n0 + tx * 8 + j];
#pragma unroll
    for (int i = 0; i < 8; ++i) {
        float* cp = C + (size_t)(m0 + ty * 8 + i) * HIDN + n0 + tx * 8;
#pragma unroll
        for (int j4 = 0; j4 < 2; ++j4) {
            float4 v;
            v.x = fmaxf(acc[i][j4 * 4 + 0] + bv[j4 * 4 + 0], 0.f);
            v.y = fmaxf(acc[i][j4 * 4 + 1] + bv[j4 * 4 + 1], 0.f);
            v.z = fmaxf(acc[i][j4 * 4 + 2] + bv[j4 * 4 + 2], 0.f);
            v.w = fmaxf(acc[i][j4 * 4 + 3] + bv[j4 * 4 + 3], 0.f);
            *(float4*)(cp + j4 * 4) = v;
        }
    }
}

// ---------------- split-bf16 MFMA GEMM ----------------
// Block 128 x (NFB*32); 4 waves as 2x2, each wave 64 x (NFB/2*32).
// A: fp32 row-major [row][512], converted to hi/lo bf16 during staging.
// B: pre-split frag-linear chunks (k_prepw*). K fixed at 512.

template<int NFB, int NOUT, bool RELU, bool GATHER, bool SCATTER>
__global__ __launch_bounds__(256, 2)
void k_mfma(const float* __restrict__ A,
            const short* __restrict__ BHg, const short* __restrict__ BLg,
            const float* __restrict__ bb, float* __restrict__ C,
            const int* __restrict__ dom_off, const int* __restrict__ rowidx,
            const int matStride, const int bStride)
{
    constexpr int BN = NFB * 32;
    constexpr int NT = NOUT / BN;
    constexpr int NF = NFB / 2;          // n-frags per wave
    constexpr int BC = NFB / 2;          // 16B B-copies per thread per array
    constexpr int BUFEL = 8192 + NFB * 2048;
    constexpr int AHo = 0, ALo = 4096, BHo = 8192, BLo = 8192 + NFB * 1024;
    __shared__ __align__(16) short sm[2][BUFEL];

    const int tid = threadIdx.x;
    const int lane = tid & 63;
    const int wm = tid >> 7;             // wave row (2x2 wave grid)
    const int wn = (tid >> 6) & 1;

    int sortBase = 0, Md = NB;
    const short* bh = BHg;
    const short* bl = BLg;
    const float* bias = bb;
    if (dom_off) {
        const int dom = blockIdx.y;
        sortBase = dom_off[dom];
        Md = dom_off[dom + 1] - sortBase;
        bh += (size_t)dom * matStride;
        bl += (size_t)dom * matStride;
        bias += dom * bStride;
    }
    const int tm = (int)blockIdx.x / NT, tn = (int)blockIdx.x % NT;
    const int m0 = tm * 128;
    if (m0 >= Md) return;

    // A staging ids: thread owns row ar, k8 chunks {ak, ak+2}
    const int ar = tid & 127;
    const int ak = tid >> 7;
    const int amf = ar >> 5;
    const int aflat0 = (amf * 4 + ak) * 256 + (ar & 31) * 8;
    const int aflat1 = (amf * 4 + 2 + ak) * 256 + (ar & 31) * 8;
    const bool aval = (m0 + ar) < Md;
    const float* ap = A;
    if (aval) {
        int g = m0 + ar;
        int src = GATHER ? rowidx[sortBase + g] : (dom_off ? sortBase + g : g);
        ap = A + (size_t)src * HIDN + ak * 8;
    }
    const short* bhp = bh + (size_t)tn * (NFB * 1024);
    const short* blp = bl + (size_t)tn * (NFB * 1024);
    const int ktB = NT * NFB * 1024;

    f32x16 acc[2][NF];
#pragma unroll
    for (int i = 0; i < 2; ++i)
#pragma unroll
        for (int j = 0; j < NF; ++j)
#pragma unroll
            for (int e = 0; e < 16; ++e) acc[i][j][e] = 0.f;

    float4 ag[4];
    bf16x8 bgh[BC], bgl[BC];

    auto ldg = [&](int kt) {
        if (aval) {
            const float* p = ap + kt * 32;
            ag[0] = *(const float4*)(p);
            ag[1] = *(const float4*)(p + 4);
            ag[2] = *(const float4*)(p + 16);
            ag[3] = *(const float4*)(p + 20);
        }
        const short* ph = bhp + (size_t)kt * ktB;
        const short* pl = blp + (size_t)kt * ktB;
#pragma unroll
        for (int c = 0; c < BC; ++c) {
            bgh[c] = *(const bf16x8*)(ph + (c * 256 + tid) * 8);
            bgl[c] = *(const bf16x8*)(pl + (c * 256 + tid) * 8);
        }
    };

    auto cvhalf = [&](const float4& x, const float4& y, uint4& h, uint4& l) {
        float xs[8] = {x.x, x.y, x.z, x.w, y.x, y.y, y.z, y.w};
        unsigned hh[8], ll[8];
#pragma unroll
        for (int i = 0; i < 8; ++i) {
            unsigned hb = bfr_hi(xs[i]);
            hh[i] = hb;
            ll[i] = bfr_hi(xs[i] - __uint_as_float(hb));
        }
        h = make_uint4((hh[0] >> 16) | (hh[1] & 0xffff0000u), (hh[2] >> 16) | (hh[3] & 0xffff0000u),
                       (hh[4] >> 16) | (hh[5] & 0xffff0000u), (hh[6] >> 16) | (hh[7] & 0xffff0000u));
        l = make_uint4((ll[0] >> 16) | (ll[1] & 0xffff0000u), (ll[2] >> 16) | (ll[3] & 0xffff0000u),
                       (ll[4] >> 16) | (ll[5] & 0xffff0000u), (ll[6] >> 16) | (ll[7] & 0xffff0000u));
    };

    auto stg = [&](int nb) {
        uint4 h0, l0, h1, l1;
        if (aval) { cvhalf(ag[0], ag[1], h0, l0); cvhalf(ag[2], ag[3], h1, l1); }
        else { h0 = l0 = h1 = l1 = make_uint4(0, 0, 0, 0); }
        *(uint4*)&sm[nb][AHo + aflat0] = h0;
        *(uint4*)&sm[nb][ALo + aflat0] = l0;
        *(uint4*)&sm[nb][AHo + aflat1] = h1;
        *(uint4*)&sm[nb][ALo + aflat1] = l1;
#pragma unroll
        for (int c = 0; c < BC; ++c) {
            *(bf16x8*)&sm[nb][BHo + (c * 256 + tid) * 8] = bgh[c];
            *(bf16x8*)&sm[nb][BLo + (c * 256 + tid) * 8] = bgl[c];
        }
    };

    auto compute = [&](int cb) {
#pragma unroll
        for (int ks = 0; ks < 2; ++ks) {
            bf16x8 fah[2], fal[2], fbh[NF], fbl[NF];
#pragma unroll
            for (int mf = 0; mf < 2; ++mf) {
                int mg = wm * 2 + mf;
                fah[mf] = *(const bf16x8*)&sm[cb][AHo + (mg * 2 + ks) * 512 + lane * 8];
                fal[mf] = *(const bf16x8*)&sm[cb][ALo + (mg * 2 + ks) * 512 + lane * 8];
            }
#pragma unroll
            for (int nf = 0; nf < NF; ++nf) {
                int ng = wn * NF + nf;
                fbh[nf] = *(const bf16x8*)&sm[cb][BHo + (ng * 2 + ks) * 512 + lane * 8];
                fbl[nf] = *(const bf16x8*)&sm[cb][BLo + (ng * 2 + ks) * 512 + lane * 8];
            }
#pragma unroll
            for (int mf = 0; mf < 2; ++mf)
#pragma unroll
                for (int nf = 0; nf < NF; ++nf) {
                    acc[mf][nf] = __builtin_amdgcn_mfma_f32_32x32x16_bf16(fah[mf], fbh[nf], acc[mf][nf], 0, 0, 0);
                    acc[mf][nf] = __builtin_amdgcn_mfma_f32_32x32x16_bf16(fah[mf], fbl[nf], acc[mf][nf], 0, 0, 0);
                    acc[mf][nf] = __builtin_amdgcn_mfma_f32_32x32x16_bf16(fal[mf], fbh[nf], acc[mf][nf], 0, 0, 0);
                }
        }
    };

    ldg(0);
    stg(0);
    __syncthreads();
    int cb = 0;
    for (int kt = 0; kt < 16; ++kt) {
        if (kt < 15) ldg(kt + 1);
        compute(cb);
        if (kt < 15) {
            stg(cb ^ 1);
            __syncthreads();
            cb ^= 1;
        }
    }

    // epilogue: bias + relu + store fp32
#pragma unroll
    for (int nf = 0; nf < NF; ++nf) {
        const int col = tn * BN + wn * (NF * 32) + nf * 32 + (lane & 31);
        const float bv = bias[col];
#pragma unroll
        for (int mf = 0; mf < 2; ++mf) {
            const int rb = m0 + wm * 64 + mf * 32 + 4 * (lane >> 5);
#pragma unroll
            for (int e = 0; e < 16; ++e) {
                const int grow = rb + (e & 3) + 8 * (e >> 2);
                if (grow < Md) {
                    float v = acc[mf][nf][e] + bv;
                    if (RELU) v = fmaxf(v, 0.f);
                    int orow = SCATTER ? rowidx[sortBase + grow]
                                       : (dom_off ? sortBase + grow : grow);
                    C[(size_t)orow * NOUT + col] = v;
                }
            }
        }
    }
}

// ---------------- launch ----------------

extern "C" void kernel_launch(void* const* d_in, const int* in_sizes, int n_in,
                              void* d_out, int out_size, void* d_ws, size_t ws_size,
                              hipStream_t stream) {
    const float* z   = (const float*)d_in[0];
    const int*   y   = (const int*)d_in[1];
    const float* W0  = (const float*)d_in[2];
    const float* b0  = (const float*)d_in[3];
    const float* W1  = (const float*)d_in[4];
    const float* b1  = (const float*)d_in[5];
    const float* W2  = (const float*)d_in[6];
    const float* b2  = (const float*)d_in[7];
    const float* W3  = (const float*)d_in[8];
    const float* b3  = (const float*)d_in[9];
    const float* Wu1 = (const float*)d_in[10];
    const float* bu1 = (const float*)d_in[11];
    const float* Wu2 = (const float*)d_in[12];
    const float* bu2 = (const float*)d_in[13];
    const float* Wu3 = (const float*)d_in[14];
    const float* bu3 = (const float*)d_in[15];
    const float* Wo  = (const float*)d_in[16];
    const float* bo  = (const float*)d_in[17];
    float* out = (float*)d_out;

    char* ws = (char*)d_ws;
    float* bufA = (float*)ws;                               // NB*512 f32
    float* bufB = bufA + (size_t)NB * HIDN;                 // NB*512 f32
    short* WH512 = (short*)(bufB + (size_t)NB * HIDN);      // 33 mats * 262144 el
    short* WL512 = WH512 + (size_t)33 * 262144;
    short* WoH   = WL512 + (size_t)33 * 262144;             // 10 * 32768 el
    short* WoL   = WoH + (size_t)10 * 32768;
    int* rowidx  = (int*)(WoL + (size_t)10 * 32768);
    int* counts  = rowidx + NB;
    int* cursors = counts + NDOM;
    int* offsets = cursors + NDOM;                          // NDOM+1

    // bucketing
    k_init<<<1, 64, 0, stream>>>(counts, cursors);
    k_hist<<<NB / 256, 256, 0, stream>>>(y, counts);
    k_scan<<<1, 64, 0, stream>>>(counts, offsets);
    k_scatter<<<NB / 256, 256, 0, stream>>>(y, offsets, cursors, rowidx);

    // weight prep (transpose + hi/lo split, frag-linear)
    k_prepw512<<<dim3(64, 33), 256, 0, stream>>>(W1, W2, W3, Wu1, Wu2, Wu3, WH512, WL512);
    k_prepwo<<<dim3(16, 10), 256, 0, stream>>>(Wo, WoH, WoL);

    // layer 0 (fp32, K=16)
    k_gemm0<<<dim3(512), 256, 0, stream>>>(z, W0, b0, bufA);

    const size_t MS = 262144;  // per-mat chunk elems (512x512)
    const dim3 gT(512), gH(512, NDOM), gO(128, NDOM);

    // trunk layers 1-3
    k_mfma<4, 512, true, false, false><<<gT, 256, 0, stream>>>(bufA, WH512 + 0 * MS, WL512 + 0 * MS, b1, bufB, nullptr, nullptr, 0, 0);
    k_mfma<4, 512, true, false, false><<<gT, 256, 0, stream>>>(bufB, WH512 + 1 * MS, WL512 + 1 * MS, b2, bufA, nullptr, nullptr, 0, 0);
    k_mfma<4, 512, true, false, false><<<gT, 256, 0, stream>>>(bufA, WH512 + 2 * MS, WL512 + 2 * MS, b3, bufB, nullptr, nullptr, 0, 0);
    // heads (domain-sorted)
    k_mfma<4, 512, true, true,  false><<<gH, 256, 0, stream>>>(bufB, WH512 + 3 * MS,  WL512 + 3 * MS,  bu1, bufA, offsets, rowidx, (int)MS, HIDN);
    k_mfma<4, 512, true, false, false><<<gH, 256, 0, stream>>>(bufA, WH512 + 13 * MS, WL512 + 13 * MS, bu2, bufB, offsets, rowidx, (int)MS, HIDN);
    k_mfma<4, 512, true, false, false><<<gH, 256, 0, stream>>>(bufB, WH512 + 23 * MS, WL512 + 23 * MS, bu3, bufA, offsets, rowidx, (int)MS, HIDN);
    // final 512->64, scatter to original order
    k_mfma<2, 64, false, false, true><<<gO, 256, 0, stream>>>(bufA, WoH, WoL, bo, out, offsets, rowidx, 32768, STYLE);
}

// Round 3
// 363.286 us; speedup vs baseline: 3.0180x; 1.4065x over previous
//
#include <hip/hip_runtime.h>

#define NB 16384
#define NDOM 10
#define HIDN 512
#define STYLE 64

typedef short bf16x8 __attribute__((ext_vector_type(8)));
typedef float f32x16 __attribute__((ext_vector_type(16)));

// ---------------- domain bucketing ----------------

__global__ void k_init(int* counts, int* cursors) {
    int t = threadIdx.x;
    if (t < NDOM) { counts[t] = 0; cursors[t] = 0; }
}

__global__ void k_hist(const int* __restrict__ y, int* __restrict__ counts) {
    int b = blockIdx.x * 256 + threadIdx.x;
    int d = (b < NB) ? y[b] : -1;
    int lane = threadIdx.x & 63;
#pragma unroll
    for (int dd = 0; dd < NDOM; ++dd) {
        unsigned long long bal = __ballot(d == dd);
        if (bal == 0ULL) continue;
        int leader = __builtin_ctzll(bal);
        if (d == dd && lane == leader)
            atomicAdd(&counts[dd], (int)__popcll(bal));
    }
}

// offsets + job table: jobs[j]=dom, jobs[266+j]=row0(sorted), jobs[532+j]=nrows, jobs[798]=njobs
__global__ void k_scan(const int* __restrict__ counts, int* __restrict__ offsets,
                       int* __restrict__ jobs) {
    if (threadIdx.x == 0) {
        int s = 0;
        for (int d = 0; d < NDOM; ++d) { offsets[d] = s; s += counts[d]; }
        offsets[NDOM] = s;
        int j = 0;
        for (int d = 0; d < NDOM; ++d) {
            int beg = offsets[d], end = offsets[d + 1];
            for (int p = beg; p < end; p += 64) {
                jobs[j] = d;
                jobs[266 + j] = p;
                jobs[532 + j] = (end - p < 64) ? (end - p) : 64;
                ++j;
            }
        }
        jobs[798] = j;
    }
}

__global__ void k_scatter(const int* __restrict__ y, const int* __restrict__ offsets,
                          int* __restrict__ cursors, int* __restrict__ rowidx) {
    int b = blockIdx.x * 256 + threadIdx.x;
    int d = (b < NB) ? y[b] : -1;
    int lane = threadIdx.x & 63;
#pragma unroll
    for (int dd = 0; dd < NDOM; ++dd) {
        unsigned long long bal = __ballot(d == dd);
        if (bal == 0ULL) continue;
        int leader = __builtin_ctzll(bal);
        int base = 0;
        if (d == dd && lane == leader)
            base = atomicAdd(&cursors[dd], (int)__popcll(bal));
        base = __shfl(base, leader);
        if (d == dd) {
            int rank = (int)__popcll(bal & ((1ULL << lane) - 1ULL));
            rowidx[offsets[dd] + base + rank] = b;
        }
    }
}

// ---------------- bf16 hi/lo split helpers ----------------

__device__ inline unsigned bfr_hi(float x) {
    unsigned u = __float_as_uint(x);
    return (u + 0x7fffu + ((u >> 16) & 1u)) & 0xffff0000u;  // RNE bf16 kept in high bits
}

__device__ __forceinline__ void cvhalf2(const float4& x, const float4& y, uint4& h, uint4& l) {
    float xs[8] = {x.x, x.y, x.z, x.w, y.x, y.y, y.z, y.w};
    unsigned hh[8], ll[8];
#pragma unroll
    for (int i = 0; i < 8; ++i) {
        unsigned hb = bfr_hi(xs[i]);
        hh[i] = hb;
        ll[i] = bfr_hi(xs[i] - __uint_as_float(hb));
    }
    h = make_uint4((hh[0] >> 16) | (hh[1] & 0xffff0000u), (hh[2] >> 16) | (hh[3] & 0xffff0000u),
                   (hh[4] >> 16) | (hh[5] & 0xffff0000u), (hh[6] >> 16) | (hh[7] & 0xffff0000u));
    l = make_uint4((ll[0] >> 16) | (ll[1] & 0xffff0000u), (ll[2] >> 16) | (ll[3] & 0xffff0000u),
                   (ll[4] >> 16) | (ll[5] & 0xffff0000u), (ll[6] >> 16) | (ll[7] & 0xffff0000u));
}

// ---------------- weight prep: transpose + split into frag-linear chunks ----
// chunk (mat,kt,tn) of 4096 shorts at ((mat*16+kt)*4+tn)*4096; within chunk
// el = (nf*2 + k8)*256 + (col&31)*8 + (k&7).  mats: 0..2=W1..W3, 3+d=Wu1, 13+d=Wu2, 23+d=Wu3

__global__ void k_prepw512(const float* __restrict__ W1, const float* __restrict__ W2,
                           const float* __restrict__ W3, const float* __restrict__ Wu1,
                           const float* __restrict__ Wu2, const float* __restrict__ Wu3,
                           short* __restrict__ WH, short* __restrict__ WL)
{
    const int mat = blockIdx.y;
    const int kt = blockIdx.x >> 2, tn = blockIdx.x & 3;
    const float* src;
    if (mat < 3) src = (mat == 0 ? W1 : (mat == 1 ? W2 : W3));
    else {
        int g = (mat - 3) / 10, d = (mat - 3) % 10;
        src = (g == 0 ? Wu1 : (g == 1 ? Wu2 : Wu3)) + (size_t)d * HIDN * HIDN;
    }
    short* dh = WH + ((size_t)(mat * 16 + kt) * 4 + tn) * 4096;
    short* dl = WL + ((size_t)(mat * 16 + kt) * 4 + tn) * 4096;
#pragma unroll
    for (int it = 0; it < 2; ++it) {
        int idx = it * 256 + threadIdx.x;
        int nl = idx & 127, k8 = idx >> 7;
        int n = tn * 128 + nl, k0 = kt * 32 + k8 * 8;
        unsigned hd[4], ld[4];
#pragma unroll
        for (int j2 = 0; j2 < 4; ++j2) {
            float x0 = src[(size_t)(k0 + j2 * 2) * HIDN + n];
            float x1 = src[(size_t)(k0 + j2 * 2 + 1) * HIDN + n];
            unsigned h0 = bfr_hi(x0), h1 = bfr_hi(x1);
            unsigned l0 = bfr_hi(x0 - __uint_as_float(h0));
            unsigned l1 = bfr_hi(x1 - __uint_as_float(h1));
            hd[j2] = (h0 >> 16) | (h1 & 0xffff0000u);
            ld[j2] = (l0 >> 16) | (l1 & 0xffff0000u);
        }
        int el = ((nl >> 5) * 4 + k8) * 256 + (nl & 31) * 8;
        *(uint4*)(dh + el) = make_uint4(hd[0], hd[1], hd[2], hd[3]);
        *(uint4*)(dl + el) = make_uint4(ld[0], ld[1], ld[2], ld[3]);
    }
}

// W0: 16x512 -> 4 tn chunks of 2048 shorts; el = (nf*2 + k8)*256 + c5*8 (k8 in {0,1})
__global__ void k_prepw0(const float* __restrict__ W0,
                         short* __restrict__ WH, short* __restrict__ WL)
{
    const int tn = blockIdx.x;
    const int t = threadIdx.x;
    const int nf = t >> 6, k8 = (t >> 5) & 1, c5 = t & 31;
    const int col = tn * 128 + nf * 32 + c5;
    const int k0 = k8 * 8;
    unsigned hd[4], ld[4];
#pragma unroll
    for (int j2 = 0; j2 < 4; ++j2) {
        float x0 = W0[(size_t)(k0 + j2 * 2) * HIDN + col];
        float x1 = W0[(size_t)(k0 + j2 * 2 + 1) * HIDN + col];
        unsigned h0 = bfr_hi(x0), h1 = bfr_hi(x1);
        unsigned l0 = bfr_hi(x0 - __uint_as_float(h0));
        unsigned l1 = bfr_hi(x1 - __uint_as_float(h1));
        hd[j2] = (h0 >> 16) | (h1 & 0xffff0000u);
        ld[j2] = (l0 >> 16) | (l1 & 0xffff0000u);
    }
    short* dh = WH + tn * 2048 + (nf * 2 + k8) * 256 + c5 * 8;
    short* dl = WL + tn * 2048 + (nf * 2 + k8) * 256 + c5 * 8;
    *(uint4*)dh = make_uint4(hd[0], hd[1], hd[2], hd[3]);
    *(uint4*)dl = make_uint4(ld[0], ld[1], ld[2], ld[3]);
}

// Wo: per dom, 16 kt chunks of 2048 shorts; el = nf*1024 + k8*256 + c5*8
__global__ void k_prepwo(const float* __restrict__ Wo,
                         short* __restrict__ WH, short* __restrict__ WL)
{
    const int mat = blockIdx.y;     // domain
    const int kt = blockIdx.x;      // 0..15
    const float* src = Wo + (size_t)mat * HIDN * STYLE;
    short* dh = WH + (size_t)(mat * 16 + kt) * 2048;
    short* dl = WL + (size_t)(mat * 16 + kt) * 2048;
    int idx = threadIdx.x;
    int nl = idx & 63, k8 = idx >> 6;
    int k0 = kt * 32 + k8 * 8;
    unsigned hd[4], ld[4];
#pragma unroll
    for (int j2 = 0; j2 < 4; ++j2) {
        float x0 = src[(size_t)(k0 + j2 * 2) * STYLE + nl];
        float x1 = src[(size_t)(k0 + j2 * 2 + 1) * STYLE + nl];
        unsigned h0 = bfr_hi(x0), h1 = bfr_hi(x1);
        unsigned l0 = bfr_hi(x0 - __uint_as_float(h0));
        unsigned l1 = bfr_hi(x1 - __uint_as_float(h1));
        hd[j2] = (h0 >> 16) | (h1 & 0xffff0000u);
        ld[j2] = (l0 >> 16) | (l1 & 0xffff0000u);
    }
    int el = ((nl >> 5) * 4 + k8) * 256 + (nl & 31) * 8;
    *(uint4*)(dh + el) = make_uint4(hd[0], hd[1], hd[2], hd[3]);
    *(uint4*)(dl + el) = make_uint4(ld[0], ld[1], ld[2], ld[3]);
}

// ---------------- fused persistent kernel ----------------
// 266 blocks x 256 threads; block = one job (<=64 rows of ONE domain, sorted order).
// h lives in LDS as frag-ready hi/lo bf16: chunk c = mf*32 + ksg (ksg = k>>4),
// short idx = c*512 + ((k>>3)&1)*256 + (r&31)*8 + (k&7).
// Wave w owns output cols [128w, 128w+128) for 512-wide layers.

#define LDB8(DST, OFF) do {                                                   \
    _Pragma("unroll")                                                         \
    for (int _nf = 0; _nf < 4; ++_nf) {                                       \
        DST[_nf * 2]     = *(const bf16x8*)(phW + (OFF) + _nf * 1024);        \
        DST[_nf * 2 + 1] = *(const bf16x8*)(plW + (OFF) + _nf * 1024);        \
    }                                                                         \
} while (0)

#define STAGE(BUF, KSG) do {                                                  \
    const int _c = (KSG);                                                     \
    bf16x8 _ah0 = *(const bf16x8*)(sH + _c * 512 + lane8);                    \
    bf16x8 _ah1 = *(const bf16x8*)(sH + (32 + _c) * 512 + lane8);             \
    bf16x8 _al0 = *(const bf16x8*)(sL + _c * 512 + lane8);                    \
    bf16x8 _al1 = *(const bf16x8*)(sL + (32 + _c) * 512 + lane8);             \
    _Pragma("unroll")                                                         \
    for (int _nf = 0; _nf < 4; ++_nf) {                                       \
        acc[0][_nf] = __builtin_amdgcn_mfma_f32_32x32x16_bf16(_ah0, BUF[_nf*2],   acc[0][_nf], 0,0,0); \
        acc[0][_nf] = __builtin_amdgcn_mfma_f32_32x32x16_bf16(_ah0, BUF[_nf*2+1], acc[0][_nf], 0,0,0); \
        acc[0][_nf] = __builtin_amdgcn_mfma_f32_32x32x16_bf16(_al0, BUF[_nf*2],   acc[0][_nf], 0,0,0); \
        acc[1][_nf] = __builtin_amdgcn_mfma_f32_32x32x16_bf16(_ah1, BUF[_nf*2],   acc[1][_nf], 0,0,0); \
        acc[1][_nf] = __builtin_amdgcn_mfma_f32_32x32x16_bf16(_ah1, BUF[_nf*2+1], acc[1][_nf], 0,0,0); \
        acc[1][_nf] = __builtin_amdgcn_mfma_f32_32x32x16_bf16(_al1, BUF[_nf*2],   acc[1][_nf], 0,0,0); \
    }                                                                         \
} while (0)

#define EPILOGUE(ACC, BIASP) do {                                             \
    _Pragma("unroll")                                                         \
    for (int _nf = 0; _nf < 4; ++_nf) {                                       \
        const int _k = w * 128 + _nf * 32 + (lane & 31);                      \
        const float _bv = (BIASP)[_k];                                        \
        const int _ib = (_k >> 4) * 512 + ((_k >> 3) & 1) * 256 + (_k & 7)    \
                        + (4 * (lane >> 5)) * 8;                              \
        _Pragma("unroll")                                                     \
        for (int _mf = 0; _mf < 2; ++_mf) {                                   \
            _Pragma("unroll")                                                 \
            for (int _e = 0; _e < 16; ++_e) {                                 \
                float _v = fmaxf(ACC[_mf][_nf][_e] + _bv, 0.f);               \
                unsigned _hb = bfr_hi(_v);                                    \
                unsigned _lb = bfr_hi(_v - __uint_as_float(_hb));             \
                int _idx = _ib + _mf * 16384 + ((_e & 3) + 8 * (_e >> 2)) * 8;\
                sH[_idx] = (short)(_hb >> 16);                                \
                sL[_idx] = (short)(_lb >> 16);                                \
            }                                                                 \
        }                                                                     \
    }                                                                         \
} while (0)

__device__ __forceinline__ void layer512(
    short* sH, short* sL,
    const short* __restrict__ WHm, const short* __restrict__ WLm,
    const float* __restrict__ bias, const int w, const int lane)
{
    const int lane8 = lane * 8;
    const short* phW = WHm + w * 4096 + lane8;
    const short* plW = WLm + w * 4096 + lane8;
    f32x16 acc[2][4];
#pragma unroll
    for (int a = 0; a < 2; ++a)
#pragma unroll
        for (int b = 0; b < 4; ++b)
#pragma unroll
            for (int e = 0; e < 16; ++e) acc[a][b][e] = 0.f;

    bf16x8 pA[8], pB[8];
    LDB8(pA, 0);
    for (int kt = 0; kt < 16; ++kt) {
        const int base = kt * 16384;
        LDB8(pB, base + 512);              // (kt, ks=1)
        STAGE(pA, kt * 2);
        const int nb = (kt < 15) ? base + 16384 : base;   // clamp: harmless re-read
        LDB8(pA, nb);                      // (kt+1, ks=0)
        STAGE(pB, kt * 2 + 1);
    }
    __syncthreads();                       // all reads of h done before overwrite
    EPILOGUE(acc, bias);
    __syncthreads();                       // new h visible to all waves
}

__global__ __launch_bounds__(256, 1)
void k_fused(const float* __restrict__ z, const int* __restrict__ rowidx,
             const int* __restrict__ jobs,
             const short* __restrict__ WH, const short* __restrict__ WL,
             const short* __restrict__ W0H, const short* __restrict__ W0L,
             const short* __restrict__ WoH, const short* __restrict__ WoL,
             const float* __restrict__ b0, const float* __restrict__ b1,
             const float* __restrict__ b2, const float* __restrict__ b3,
             const float* __restrict__ bu1, const float* __restrict__ bu2,
             const float* __restrict__ bu3, const float* __restrict__ bo,
             float* __restrict__ out)
{
    __shared__ short sH[32768];   // 64 KiB
    __shared__ short sL[32768];   // 64 KiB

    // bijective XCD-chunked swizzle over nwg=266 (q=33, r=2): consecutive jobs
    // (same domain) land on the same XCD -> head weights L2-resident.
    const int xcd = blockIdx.x & 7, pos = blockIdx.x >> 3;
    const int job = (xcd < 2 ? xcd * 34 : 68 + (xcd - 2) * 33) + pos;
    if (job >= jobs[798]) return;
    const int dom  = jobs[job];
    const int row0 = jobs[266 + job];
    const int nr   = jobs[532 + job];

    const int tid = threadIdx.x;
    const int lane = tid & 63;
    const int w = tid >> 6;
    const int lane8 = lane * 8;

    // ---- layer 0: z (K=16) -> h ----
    {
        bf16x8 zah[2], zal[2];
#pragma unroll
        for (int mf = 0; mf < 2; ++mf) {
            int r = mf * 32 + (lane & 31);
            float4 f0 = make_float4(0.f, 0.f, 0.f, 0.f), f1 = f0;
            if (r < nr) {
                int src = rowidx[row0 + r];
                const float* zp = z + (size_t)src * 16 + (lane >> 5) * 8;
                f0 = *(const float4*)zp;
                f1 = *(const float4*)(zp + 4);
            }
            uint4 h, l;
            cvhalf2(f0, f1, h, l);
            zah[mf] = *(bf16x8*)&h;
            zal[mf] = *(bf16x8*)&l;
        }
        f32x16 acc[2][4];
#pragma unroll
        for (int a = 0; a < 2; ++a)
#pragma unroll
            for (int b = 0; b < 4; ++b)
#pragma unroll
                for (int e = 0; e < 16; ++e) acc[a][b][e] = 0.f;
        const short* ph0 = W0H + w * 2048 + lane8;
        const short* pl0 = W0L + w * 2048 + lane8;
#pragma unroll
        for (int nf = 0; nf < 4; ++nf) {
            bf16x8 bh = *(const bf16x8*)(ph0 + nf * 512);
            bf16x8 bl = *(const bf16x8*)(pl0 + nf * 512);
#pragma unroll
            for (int mf = 0; mf < 2; ++mf) {
                acc[mf][nf] = __builtin_amdgcn_mfma_f32_32x32x16_bf16(zah[mf], bh, acc[mf][nf], 0, 0, 0);
                acc[mf][nf] = __builtin_amdgcn_mfma_f32_32x32x16_bf16(zah[mf], bl, acc[mf][nf], 0, 0, 0);
                acc[mf][nf] = __builtin_amdgcn_mfma_f32_32x32x16_bf16(zal[mf], bh, acc[mf][nf], 0, 0, 0);
            }
        }
        EPILOGUE(acc, b0);
        __syncthreads();
    }

    // ---- trunk layers 1-3 (shared weights) ----
    layer512(sH, sL, WH + (size_t)0 * 262144, WL + (size_t)0 * 262144, b1, w, lane);
    layer512(sH, sL, WH + (size_t)1 * 262144, WL + (size_t)1 * 262144, b2, w, lane);
    layer512(sH, sL, WH + (size_t)2 * 262144, WL + (size_t)2 * 262144, b3, w, lane);
    // ---- head layers (per-domain weights) ----
    layer512(sH, sL, WH + (size_t)(3 + dom) * 262144,  WL + (size_t)(3 + dom) * 262144,  bu1 + dom * HIDN, w, lane);
    layer512(sH, sL, WH + (size_t)(13 + dom) * 262144, WL + (size_t)(13 + dom) * 262144, bu2 + dom * HIDN, w, lane);
    layer512(sH, sL, WH + (size_t)(23 + dom) * 262144, WL + (size_t)(23 + dom) * 262144, bu3 + dom * HIDN, w, lane);

    // ---- final 512->64, scatter to original rows (waves 0,1 only; nf = w) ----
    if (w < 2) {
        f32x16 fa[2];
#pragma unroll
        for (int a = 0; a < 2; ++a)
#pragma unroll
            for (int e = 0; e < 16; ++e) fa[a][e] = 0.f;
        const short* ph = WoH + (size_t)dom * 32768 + w * 1024 + lane8;
        const short* pl = WoL + (size_t)dom * 32768 + w * 1024 + lane8;
        for (int kt = 0; kt < 16; ++kt) {
#pragma unroll
            for (int ks = 0; ks < 2; ++ks) {
                bf16x8 bh = *(const bf16x8*)(ph + kt * 2048 + ks * 512);
                bf16x8 bl = *(const bf16x8*)(pl + kt * 2048 + ks * 512);
                const int c = kt * 2 + ks;
                bf16x8 ah0 = *(const bf16x8*)(sH + c * 512 + lane8);
                bf16x8 ah1 = *(const bf16x8*)(sH + (32 + c) * 512 + lane8);
                bf16x8 al0 = *(const bf16x8*)(sL + c * 512 + lane8);
                bf16x8 al1 = *(const bf16x8*)(sL + (32 + c) * 512 + lane8);
                fa[0] = __builtin_amdgcn_mfma_f32_32x32x16_bf16(ah0, bh, fa[0], 0, 0, 0);
                fa[0] = __builtin_amdgcn_mfma_f32_32x32x16_bf16(ah0, bl, fa[0], 0, 0, 0);
                fa[0] = __builtin_amdgcn_mfma_f32_32x32x16_bf16(al0, bh, fa[0], 0, 0, 0);
                fa[1] = __builtin_amdgcn_mfma_f32_32x32x16_bf16(ah1, bh, fa[1], 0, 0, 0);
                fa[1] = __builtin_amdgcn_mfma_f32_32x32x16_bf16(ah1, bl, fa[1], 0, 0, 0);
                fa[1] = __builtin_amdgcn_mfma_f32_32x32x16_bf16(al1, bh, fa[1], 0, 0, 0);
            }
        }
        const int c = w * 32 + (lane & 31);
        const float bv = bo[dom * STYLE + c];
#pragma unroll
        for (int mf = 0; mf < 2; ++mf)
#pragma unroll
            for (int e = 0; e < 16; ++e) {
                int r = mf * 32 + 4 * (lane >> 5) + (e & 3) + 8 * (e >> 2);
                if (r < nr) {
                    int orow = rowidx[row0 + r];
                    out[(size_t)orow * STYLE + c] = fa[mf][e] + bv;
                }
            }
    }
}

// ---------------- launch ----------------

extern "C" void kernel_launch(void* const* d_in, const int* in_sizes, int n_in,
                              void* d_out, int out_size, void* d_ws, size_t ws_size,
                              hipStream_t stream) {
    const float* z   = (const float*)d_in[0];
    const int*   y   = (const int*)d_in[1];
    const float* W0  = (const float*)d_in[2];
    const float* b0  = (const float*)d_in[3];
    const float* W1  = (const float*)d_in[4];
    const float* b1  = (const float*)d_in[5];
    const float* W2  = (const float*)d_in[6];
    const float* b2  = (const float*)d_in[7];
    const float* W3  = (const float*)d_in[8];
    const float* b3  = (const float*)d_in[9];
    const float* Wu1 = (const float*)d_in[10];
    const float* bu1 = (const float*)d_in[11];
    const float* Wu2 = (const float*)d_in[12];
    const float* bu2 = (const float*)d_in[13];
    const float* Wu3 = (const float*)d_in[14];
    const float* bu3 = (const float*)d_in[15];
    const float* Wo  = (const float*)d_in[16];
    const float* bo  = (const float*)d_in[17];
    float* out = (float*)d_out;

    short* WH512 = (short*)d_ws;                            // 33 * 262144 shorts
    short* WL512 = WH512 + (size_t)33 * 262144;
    short* W0H   = WL512 + (size_t)33 * 262144;             // 8192
    short* W0L   = W0H + 8192;
    short* WoH   = W0L + 8192;                              // 10 * 32768
    short* WoL   = WoH + (size_t)10 * 32768;
    int* rowidx  = (int*)(WoL + (size_t)10 * 32768);        // NB
    int* counts  = rowidx + NB;                             // NDOM
    int* cursors = counts + NDOM;                           // NDOM
    int* offsets = cursors + NDOM;                          // NDOM+1
    int* jobs    = offsets + NDOM + 1;                      // 799 ints

    // bucketing + job table
    k_init<<<1, 64, 0, stream>>>(counts, cursors);
    k_hist<<<NB / 256, 256, 0, stream>>>(y, counts);
    k_scan<<<1, 64, 0, stream>>>(counts, offsets, jobs);
    k_scatter<<<NB / 256, 256, 0, stream>>>(y, offsets, cursors, rowidx);

    // weight prep (transpose + hi/lo split, frag-linear)
    k_prepw512<<<dim3(64, 33), 256, 0, stream>>>(W1, W2, W3, Wu1, Wu2, Wu3, WH512, WL512);
    k_prepw0<<<4, 256, 0, stream>>>(W0, W0H, W0L);
    k_prepwo<<<dim3(16, 10), 256, 0, stream>>>(Wo, WoH, WoL);

    // fused network
    k_fused<<<266, 256, 0, stream>>>(z, rowidx, jobs, WH512, WL512, W0H, W0L, WoH, WoL,
                                     b0, b1, b2, b3, bu1, bu2, bu3, bo, out);
}

// Round 4
// 219.644 us; speedup vs baseline: 4.9918x; 1.6540x over previous
//
#include <hip/hip_runtime.h>

#define NB 16384
#define NDOM 10
#define HIDN 512
#define STYLE 64
#define NWIN 256   // NB / 64

typedef short bf16x8 __attribute__((ext_vector_type(8)));
typedef float f32x16 __attribute__((ext_vector_type(16)));

// ---------------- bf16 helpers ----------------

__device__ __forceinline__ unsigned bfr_hi(float x) {
    unsigned u = __float_as_uint(x);
    return (u + 0x7fffu + ((u >> 16) & 1u)) & 0xffff0000u;  // RNE bf16 in high bits
}
__device__ __forceinline__ short bfs(float x) { return (short)(bfr_hi(x) >> 16); }

__device__ __forceinline__ void cvhalf2(const float4& x, const float4& y, uint4& h, uint4& l) {
    float xs[8] = {x.x, x.y, x.z, x.w, y.x, y.y, y.z, y.w};
    unsigned hh[8], ll[8];
#pragma unroll
    for (int i = 0; i < 8; ++i) {
        unsigned hb = bfr_hi(xs[i]);
        hh[i] = hb;
        ll[i] = bfr_hi(xs[i] - __uint_as_float(hb));
    }
    h = make_uint4((hh[0] >> 16) | (hh[1] & 0xffff0000u), (hh[2] >> 16) | (hh[3] & 0xffff0000u),
                   (hh[4] >> 16) | (hh[5] & 0xffff0000u), (hh[6] >> 16) | (hh[7] & 0xffff0000u));
    l = make_uint4((ll[0] >> 16) | (ll[1] & 0xffff0000u), (ll[2] >> 16) | (ll[3] & 0xffff0000u),
                   (ll[4] >> 16) | (ll[5] & 0xffff0000u), (ll[6] >> 16) | (ll[7] & 0xffff0000u));
}

// ---------------- bucketing: histogram + scan (1 block), then scatter ------

__global__ void k_buckets(const int* __restrict__ y, int* __restrict__ offsets,
                          int* __restrict__ cursors) {
    __shared__ int hist[NDOM];
    const int t = threadIdx.x;            // 1024 threads
    if (t < NDOM) hist[t] = 0;
    __syncthreads();
    const int lane = t & 63;
    for (int i = 0; i < NB; i += 1024) {
        int d = y[i + t];
#pragma unroll
        for (int dd = 0; dd < NDOM; ++dd) {
            unsigned long long bal = __ballot(d == dd);
            if (bal != 0ULL && lane == __builtin_ctzll(bal))
                atomicAdd(&hist[dd], (int)__popcll(bal));
        }
    }
    __syncthreads();
    if (t == 0) {
        int s = 0;
        for (int d = 0; d < NDOM; ++d) { offsets[d] = s; s += hist[d]; }
        offsets[NDOM] = s;
    }
    if (t < NDOM) cursors[t] = 0;
}

__global__ void k_scatter(const int* __restrict__ y, const int* __restrict__ offsets,
                          int* __restrict__ cursors, int* __restrict__ rowidx) {
    int b = blockIdx.x * 256 + threadIdx.x;
    int d = (b < NB) ? y[b] : -1;
    int lane = threadIdx.x & 63;
#pragma unroll
    for (int dd = 0; dd < NDOM; ++dd) {
        unsigned long long bal = __ballot(d == dd);
        if (bal == 0ULL) continue;
        int leader = __builtin_ctzll(bal);
        int base = 0;
        if (d == dd && lane == leader)
            base = atomicAdd(&cursors[dd], (int)__popcll(bal));
        base = __shfl(base, leader);
        if (d == dd) {
            int rank = (int)__popcll(bal & ((1ULL << lane) - 1ULL));
            rowidx[offsets[dd] + base + rank] = b;
        }
    }
}

// ---------------- unified weight prep (single bf16, frag-linear) ----------
// Big mats (512x512): per (mat, w) block of 32768 shorts:
//   addr = ks*1024 + nf*512 + k8*256 + c5*8 + j ; k = ks*16+k8*8+j, col = w*64+nf*32+c5
// mats: 0..2 = W1..W3 ; 3+d = Wu1[d] ; 13+d = Wu2[d] ; 23+d = Wu3[d]
// W0 (16x512): granule g: w=g>>7, nf=(g>>6)&1, k8=(g>>5)&1, c5=g&31 at W0p+g*8
// Wo (per dom 512x64): granule g: w1=g>>11, ks=(g>>6)&31, k8=(g>>5)&1, c5=g&31

__global__ void k_prep(const float* __restrict__ W1, const float* __restrict__ W2,
                       const float* __restrict__ W3, const float* __restrict__ Wu1,
                       const float* __restrict__ Wu2, const float* __restrict__ Wu3,
                       const float* __restrict__ W0, const float* __restrict__ Wo,
                       short* __restrict__ Wp, short* __restrict__ W0p,
                       short* __restrict__ WoP)
{
    const int b = blockIdx.x;
    const int t = threadIdx.x;
    if (b < 264) {
        __shared__ float Ld[64][66];
        const int mat = b >> 3, w = b & 7;
        const float* src;
        if (mat < 3) src = (mat == 0 ? W1 : (mat == 1 ? W2 : W3));
        else {
            int g = (mat - 3) / 10, d = (mat - 3) % 10;
            src = (g == 0 ? Wu1 : (g == 1 ? Wu2 : Wu3)) + (size_t)d * HIDN * HIDN;
        }
        short* dst = Wp + (size_t)mat * 262144 + w * 32768;
        for (int s = 0; s < 8; ++s) {
            __syncthreads();
            const int r4 = t >> 6, c = t & 63;
#pragma unroll
            for (int p = 0; p < 16; ++p) {
                int k = s * 64 + p * 4 + r4;
                Ld[p * 4 + r4][c] = src[(size_t)k * HIDN + w * 64 + c];
            }
            __syncthreads();
#pragma unroll
            for (int i = 0; i < 2; ++i) {
                int g = i * 256 + t;
                int ksl = g >> 7, nf = (g >> 6) & 1, k8 = (g >> 5) & 1, c5 = g & 31;
                int kk = ksl * 16 + k8 * 8;
                unsigned pk[4];
#pragma unroll
                for (int j2 = 0; j2 < 4; ++j2) {
                    unsigned h0 = bfr_hi(Ld[kk + 2 * j2][nf * 32 + c5]);
                    unsigned h1 = bfr_hi(Ld[kk + 2 * j2 + 1][nf * 32 + c5]);
                    pk[j2] = (h0 >> 16) | (h1 & 0xffff0000u);
                }
                int ksg = s * 4 + ksl;
                *(uint4*)(dst + ksg * 1024 + nf * 512 + k8 * 256 + c5 * 8) =
                    make_uint4(pk[0], pk[1], pk[2], pk[3]);
            }
        }
    } else if (b == 264) {
#pragma unroll
        for (int i = 0; i < 4; ++i) {
            int g = i * 256 + t;   // 1024 granules
            int w = g >> 7, nf = (g >> 6) & 1, k8 = (g >> 5) & 1, c5 = g & 31;
            int col = w * 64 + nf * 32 + c5;
            unsigned pk[4];
#pragma unroll
            for (int j2 = 0; j2 < 4; ++j2) {
                unsigned h0 = bfr_hi(W0[(size_t)(k8 * 8 + 2 * j2) * HIDN + col]);
                unsigned h1 = bfr_hi(W0[(size_t)(k8 * 8 + 2 * j2 + 1) * HIDN + col]);
                pk[j2] = (h0 >> 16) | (h1 & 0xffff0000u);
            }
            *(uint4*)(W0p + g * 8) = make_uint4(pk[0], pk[1], pk[2], pk[3]);
        }
    } else {
        const int dom = b - 265;
        const float* src = Wo + (size_t)dom * HIDN * STYLE;
        short* dst = WoP + (size_t)dom * 32768;
#pragma unroll
        for (int i = 0; i < 16; ++i) {
            int g = i * 256 + t;   // 4096 granules
            int w1 = g >> 11, ks = (g >> 6) & 31, k8 = (g >> 5) & 1, c5 = g & 31;
            int col = w1 * 32 + c5;
            int k0 = ks * 16 + k8 * 8;
            unsigned pk[4];
#pragma unroll
            for (int j2 = 0; j2 < 4; ++j2) {
                unsigned h0 = bfr_hi(src[(size_t)(k0 + 2 * j2) * STYLE + col]);
                unsigned h1 = bfr_hi(src[(size_t)(k0 + 2 * j2 + 1) * STYLE + col]);
                pk[j2] = (h0 >> 16) | (h1 & 0xffff0000u);
            }
            *(uint4*)(dst + g * 8) = make_uint4(pk[0], pk[1], pk[2], pk[3]);
        }
    }
}

// ---------------- fused persistent kernel ----------------
// 256 blocks x 512 threads (8 waves). Block = 64 sorted rows [64*win, 64*win+64).
// h in LDS as hi/lo bf16, swizzled: for (row, k): octet o=k>>3, j=k&7,
//   idx = o*512 + ((row ^ (o&3)) * 8) + j.
// Wave w owns cols [64w, 64w+64): mf=2 (rows 0-31/32-63), nf=2.
// Weights single bf16, streamed global->VGPR, depth-2 prefetch.

__device__ __forceinline__ void ldw2(const short* p, int lane, bf16x8 b[2]) {
    b[0] = *(const bf16x8*)(p + lane * 8);
    b[1] = *(const bf16x8*)(p + 512 + lane * 8);
}

__device__ __forceinline__ void doks(const short* sH, const short* sL, int ks, int lane,
                                     const bf16x8 b[2], f32x16 acc[2][2]) {
    const int o = 2 * ks + (lane >> 5);
    const int base = o * 512 + (((lane & 31) ^ (o & 3)) * 8);
    bf16x8 ah0 = *(const bf16x8*)&sH[base];
    bf16x8 al0 = *(const bf16x8*)&sL[base];
    bf16x8 ah1 = *(const bf16x8*)&sH[base + 256];
    bf16x8 al1 = *(const bf16x8*)&sL[base + 256];
    acc[0][0] = __builtin_amdgcn_mfma_f32_32x32x16_bf16(ah0, b[0], acc[0][0], 0, 0, 0);
    acc[0][0] = __builtin_amdgcn_mfma_f32_32x32x16_bf16(al0, b[0], acc[0][0], 0, 0, 0);
    acc[0][1] = __builtin_amdgcn_mfma_f32_32x32x16_bf16(ah0, b[1], acc[0][1], 0, 0, 0);
    acc[0][1] = __builtin_amdgcn_mfma_f32_32x32x16_bf16(al0, b[1], acc[0][1], 0, 0, 0);
    acc[1][0] = __builtin_amdgcn_mfma_f32_32x32x16_bf16(ah1, b[0], acc[1][0], 0, 0, 0);
    acc[1][0] = __builtin_amdgcn_mfma_f32_32x32x16_bf16(al1, b[0], acc[1][0], 0, 0, 0);
    acc[1][1] = __builtin_amdgcn_mfma_f32_32x32x16_bf16(ah1, b[1], acc[1][1], 0, 0, 0);
    acc[1][1] = __builtin_amdgcn_mfma_f32_32x32x16_bf16(al1, b[1], acc[1][1], 0, 0, 0);
}

__device__ __forceinline__ void compute512(const short* sH, const short* sL,
                                           const short* pW, int lane, f32x16 acc[2][2]) {
#pragma unroll
    for (int a = 0; a < 2; ++a)
#pragma unroll
        for (int b = 0; b < 2; ++b)
#pragma unroll
            for (int e = 0; e < 16; ++e) acc[a][b][e] = 0.f;
    bf16x8 cur[2], nxt[2];
    ldw2(pW, lane, cur);
    ldw2(pW + 1024, lane, nxt);
#pragma unroll
    for (int ks = 0; ks < 32; ++ks) {
        bf16x8 now[2] = {cur[0], cur[1]};
        cur[0] = nxt[0]; cur[1] = nxt[1];
        if (ks < 30) ldw2(pW + (ks + 2) * 1024, lane, nxt);
        doks(sH, sL, ks, lane, now, acc);
    }
}

__device__ __forceinline__ void epi512(short* sH, short* sL, const f32x16 acc[2][2],
                                       const float* bias, int w, int lane,
                                       int rlo, int rhi) {
#pragma unroll
    for (int nf = 0; nf < 2; ++nf) {
        const int k = w * 64 + nf * 32 + (lane & 31);
        const float bv = bias[k];
        const int o = k >> 3, jb = k & 7, swz = o & 3;
#pragma unroll
        for (int mf = 0; mf < 2; ++mf) {
            const int rb = 32 * mf + 4 * (lane >> 5);
#pragma unroll
            for (int e = 0; e < 16; ++e) {
                const int row = rb + (e & 3) + 8 * (e >> 2);
                if (row >= rlo && row < rhi) {
                    float v = fmaxf(acc[mf][nf][e] + bv, 0.f);
                    unsigned hb = bfr_hi(v);
                    short lb = bfs(v - __uint_as_float(hb));
                    int idx = o * 512 + ((row ^ swz) * 8) + jb;
                    sH[idx] = (short)(hb >> 16);
                    sL[idx] = lb;
                }
            }
        }
    }
}

__global__ __launch_bounds__(512, 2)
void k_fused(const float* __restrict__ z, const int* __restrict__ rowidx,
             const int* __restrict__ offsets,
             const short* __restrict__ Wp, const short* __restrict__ W0p,
             const short* __restrict__ WoP,
             const float* __restrict__ b0, const float* __restrict__ b1,
             const float* __restrict__ b2, const float* __restrict__ b3,
             const float* __restrict__ bu1, const float* __restrict__ bu2,
             const float* __restrict__ bu3, const float* __restrict__ bo,
             float* __restrict__ out)
{
    __shared__ short sH[32768];   // 64 KiB
    __shared__ short sL[32768];   // 64 KiB
    __shared__ int soff[NDOM + 1];

    // XCD-chunked swizzle (256 = 8*32, bijective): neighbors share a domain -> L2 reuse
    const int win = (blockIdx.x & 7) * 32 + (blockIdx.x >> 3);
    const int row0 = win * 64;
    const int tid = threadIdx.x;
    const int lane = tid & 63;
    const int w = tid >> 6;

    if (tid < NDOM + 1) soff[tid] = offsets[tid];

    f32x16 acc[2][2];

    // ---- layer 0: z (K=16) -> h ----
    {
#pragma unroll
        for (int a = 0; a < 2; ++a)
#pragma unroll
            for (int b = 0; b < 2; ++b)
#pragma unroll
                for (int e = 0; e < 16; ++e) acc[a][b][e] = 0.f;
        bf16x8 bw[2];
        bw[0] = *(const bf16x8*)&W0p[w * 1024 + lane * 8];
        bw[1] = *(const bf16x8*)&W0p[w * 1024 + 512 + lane * 8];
#pragma unroll
        for (int mf = 0; mf < 2; ++mf) {
            int r = mf * 32 + (lane & 31);
            int src = rowidx[row0 + r];
            const float* zp = z + (size_t)src * 16 + (lane >> 5) * 8;
            float4 f0 = *(const float4*)zp;
            float4 f1 = *(const float4*)(zp + 4);
            uint4 h, l;
            cvhalf2(f0, f1, h, l);
            bf16x8 zah = *(bf16x8*)&h;
            bf16x8 zal = *(bf16x8*)&l;
            acc[mf][0] = __builtin_amdgcn_mfma_f32_32x32x16_bf16(zah, bw[0], acc[mf][0], 0, 0, 0);
            acc[mf][0] = __builtin_amdgcn_mfma_f32_32x32x16_bf16(zal, bw[0], acc[mf][0], 0, 0, 0);
            acc[mf][1] = __builtin_amdgcn_mfma_f32_32x32x16_bf16(zah, bw[1], acc[mf][1], 0, 0, 0);
            acc[mf][1] = __builtin_amdgcn_mfma_f32_32x32x16_bf16(zal, bw[1], acc[mf][1], 0, 0, 0);
        }
        epi512(sH, sL, acc, b0, w, lane, 0, 64);
        __syncthreads();
    }

    // ---- trunk layers 1-3 ----
#pragma unroll 1
    for (int m = 0; m < 3; ++m) {
        const float* bp = (m == 0) ? b1 : (m == 1) ? b2 : b3;
        compute512(sH, sL, Wp + (size_t)m * 262144 + w * 32768, lane, acc);
        __syncthreads();
        epi512(sH, sL, acc, bp, w, lane, 0, 64);
        __syncthreads();
    }

    // ---- head layers (per-domain segments; MFMA rows are independent) ----
#pragma unroll 1
    for (int L = 0; L < 3; ++L) {
        const short* WpL = Wp + (size_t)(3 + L * 10) * 262144;
        const float* buL = (L == 0) ? bu1 : (L == 1) ? bu2 : bu3;
#pragma unroll 1
        for (int d = 0; d < NDOM; ++d) {
            int rlo = soff[d] - row0, rhi = soff[d + 1] - row0;
            rlo = rlo < 0 ? 0 : rlo;
            rhi = rhi > 64 ? 64 : rhi;
            if (rhi <= rlo) continue;
            compute512(sH, sL, WpL + (size_t)d * 262144 + w * 32768, lane, acc);
            __syncthreads();
            epi512(sH, sL, acc, buL + d * HIDN, w, lane, rlo, rhi);
            __syncthreads();
        }
    }

    // ---- final 512->64, scatter to original rows (waves 0-1) ----
    if (w < 2) {
#pragma unroll 1
        for (int d = 0; d < NDOM; ++d) {
            int rlo = soff[d] - row0, rhi = soff[d + 1] - row0;
            rlo = rlo < 0 ? 0 : rlo;
            rhi = rhi > 64 ? 64 : rhi;
            if (rhi <= rlo) continue;
            f32x16 fa[2];
#pragma unroll
            for (int a = 0; a < 2; ++a)
#pragma unroll
                for (int e = 0; e < 16; ++e) fa[a][e] = 0.f;
            const short* pw = WoP + (size_t)d * 32768 + w * 16384;
#pragma unroll
            for (int ks = 0; ks < 32; ++ks) {
                bf16x8 bwv = *(const bf16x8*)(pw + ks * 512 + lane * 8);
                const int o = 2 * ks + (lane >> 5);
                const int base = o * 512 + (((lane & 31) ^ (o & 3)) * 8);
                bf16x8 ah0 = *(const bf16x8*)&sH[base];
                bf16x8 al0 = *(const bf16x8*)&sL[base];
                bf16x8 ah1 = *(const bf16x8*)&sH[base + 256];
                bf16x8 al1 = *(const bf16x8*)&sL[base + 256];
                fa[0] = __builtin_amdgcn_mfma_f32_32x32x16_bf16(ah0, bwv, fa[0], 0, 0, 0);
                fa[0] = __builtin_amdgcn_mfma_f32_32x32x16_bf16(al0, bwv, fa[0], 0, 0, 0);
                fa[1] = __builtin_amdgcn_mfma_f32_32x32x16_bf16(ah1, bwv, fa[1], 0, 0, 0);
                fa[1] = __builtin_amdgcn_mfma_f32_32x32x16_bf16(al1, bwv, fa[1], 0, 0, 0);
            }
            const int c = w * 32 + (lane & 31);
            const float bv = bo[d * STYLE + c];
#pragma unroll
            for (int mf = 0; mf < 2; ++mf)
#pragma unroll
                for (int e = 0; e < 16; ++e) {
                    int row = 32 * mf + 4 * (lane >> 5) + (e & 3) + 8 * (e >> 2);
                    if (row >= rlo && row < rhi) {
                        int orow = rowidx[row0 + row];
                        out[(size_t)orow * STYLE + c] = fa[mf][e] + bv;
                    }
                }
        }
    }
}

// ---------------- launch ----------------

extern "C" void kernel_launch(void* const* d_in, const int* in_sizes, int n_in,
                              void* d_out, int out_size, void* d_ws, size_t ws_size,
                              hipStream_t stream) {
    const float* z   = (const float*)d_in[0];
    const int*   y   = (const int*)d_in[1];
    const float* W0  = (const float*)d_in[2];
    const float* b0  = (const float*)d_in[3];
    const float* W1  = (const float*)d_in[4];
    const float* b1  = (const float*)d_in[5];
    const float* W2  = (const float*)d_in[6];
    const float* b2  = (const float*)d_in[7];
    const float* W3  = (const float*)d_in[8];
    const float* b3  = (const float*)d_in[9];
    const float* Wu1 = (const float*)d_in[10];
    const float* bu1 = (const float*)d_in[11];
    const float* Wu2 = (const float*)d_in[12];
    const float* bu2 = (const float*)d_in[13];
    const float* Wu3 = (const float*)d_in[14];
    const float* bu3 = (const float*)d_in[15];
    const float* Wo  = (const float*)d_in[16];
    const float* bo  = (const float*)d_in[17];
    float* out = (float*)d_out;

    short* Wp   = (short*)d_ws;                      // 33 * 262144 shorts (16.5 MB)
    short* W0p  = Wp + (size_t)33 * 262144;          // 8192 shorts
    short* WoP  = W0p + 8192;                        // 10 * 32768 shorts
    int* rowidx  = (int*)(WoP + (size_t)10 * 32768); // NB ints
    int* offsets = rowidx + NB;                      // NDOM+1
    int* cursors = offsets + NDOM + 1;               // NDOM

    k_buckets<<<1, 1024, 0, stream>>>(y, offsets, cursors);
    k_scatter<<<NB / 256, 256, 0, stream>>>(y, offsets, cursors, rowidx);
    k_prep<<<275, 256, 0, stream>>>(W1, W2, W3, Wu1, Wu2, Wu3, W0, Wo, Wp, W0p, WoP);
    k_fused<<<NWIN, 512, 0, stream>>>(z, rowidx, offsets, Wp, W0p, WoP,
                                      b0, b1, b2, b3, bu1, bu2, bu3, bo, out);
}

// Round 5
// 206.416 us; speedup vs baseline: 5.3116x; 1.0641x over previous
//
#include <hip/hip_runtime.h>

#define NB 16384
#define NDOM 10
#define HIDN 512
#define STYLE 64
#define NWIN 256   // NB / 64

typedef short bf16x8 __attribute__((ext_vector_type(8)));
typedef float f32x16 __attribute__((ext_vector_type(16)));

#define MFMA __builtin_amdgcn_mfma_f32_32x32x16_bf16

// ---------------- bf16 helpers ----------------

__device__ __forceinline__ unsigned bfr_hi(float x) {
    unsigned u = __float_as_uint(x);
    return (u + 0x7fffu + ((u >> 16) & 1u)) & 0xffff0000u;  // RNE bf16 in high bits
}

__device__ __forceinline__ unsigned cvtpk(float a, float b) {
    unsigned r;
    asm("v_cvt_pk_bf16_f32 %0, %1, %2" : "=v"(r) : "v"(a), "v"(b));
    return r;   // [15:0]=bf16(a), [31:16]=bf16(b)
}

__device__ __forceinline__ void cvhalf2(const float4& x, const float4& y, uint4& h, uint4& l) {
    float xs[8] = {x.x, x.y, x.z, x.w, y.x, y.y, y.z, y.w};
    unsigned hh[8], ll[8];
#pragma unroll
    for (int i = 0; i < 8; ++i) {
        unsigned hb = bfr_hi(xs[i]);
        hh[i] = hb;
        ll[i] = bfr_hi(xs[i] - __uint_as_float(hb));
    }
    h = make_uint4((hh[0] >> 16) | (hh[1] & 0xffff0000u), (hh[2] >> 16) | (hh[3] & 0xffff0000u),
                   (hh[4] >> 16) | (hh[5] & 0xffff0000u), (hh[6] >> 16) | (hh[7] & 0xffff0000u));
    l = make_uint4((ll[0] >> 16) | (ll[1] & 0xffff0000u), (ll[2] >> 16) | (ll[3] & 0xffff0000u),
                   (ll[4] >> 16) | (ll[5] & 0xffff0000u), (ll[6] >> 16) | (ll[7] & 0xffff0000u));
}

// ---------------- bucketing ----------------

__global__ void k_buckets(const int* __restrict__ y, int* __restrict__ offsets,
                          int* __restrict__ cursors) {
    __shared__ int hist[NDOM];
    const int t = threadIdx.x;            // 1024 threads
    if (t < NDOM) hist[t] = 0;
    __syncthreads();
    const int lane = t & 63;
    for (int i = 0; i < NB; i += 1024) {
        int d = y[i + t];
#pragma unroll
        for (int dd = 0; dd < NDOM; ++dd) {
            unsigned long long bal = __ballot(d == dd);
            if (bal != 0ULL && lane == __builtin_ctzll(bal))
                atomicAdd(&hist[dd], (int)__popcll(bal));
        }
    }
    __syncthreads();
    if (t == 0) {
        int s = 0;
        for (int d = 0; d < NDOM; ++d) { offsets[d] = s; s += hist[d]; }
        offsets[NDOM] = s;
    }
    if (t < NDOM) cursors[t] = 0;
}

__global__ void k_scatter(const int* __restrict__ y, const int* __restrict__ offsets,
                          int* __restrict__ cursors, int* __restrict__ rowidx) {
    int b = blockIdx.x * 256 + threadIdx.x;
    int d = (b < NB) ? y[b] : -1;
    int lane = threadIdx.x & 63;
#pragma unroll
    for (int dd = 0; dd < NDOM; ++dd) {
        unsigned long long bal = __ballot(d == dd);
        if (bal == 0ULL) continue;
        int leader = __builtin_ctzll(bal);
        int base = 0;
        if (d == dd && lane == leader)
            base = atomicAdd(&cursors[dd], (int)__popcll(bal));
        base = __shfl(base, leader);
        if (d == dd) {
            int rank = (int)__popcll(bal & ((1ULL << lane) - 1ULL));
            rowidx[offsets[dd] + base + rank] = b;
        }
    }
}

// ---------------- weight prep (single bf16, frag-linear) -------------------
// Big mats (512x512): per (mat, w) block of 32768 shorts:
//   addr = ks*1024 + of*512 + k8*256 + c5*8 + j ; k = ks*16+k8*8+j, col = w*64+of*32+c5
// mats: 0..2 = W1..W3 ; 3+d = Wu1[d] ; 13+d = Wu2[d] ; 23+d = Wu3[d]
// W0 (16x512): granule g: w=g>>7, of=(g>>6)&1, k8=(g>>5)&1, c5=g&31 at W0p+g*8
// Wo (per dom 512x64): granule g: w1=g>>11, ks=(g>>6)&31, k8=(g>>5)&1, c5=g&31

__global__ void k_prep(const float* __restrict__ W1, const float* __restrict__ W2,
                       const float* __restrict__ W3, const float* __restrict__ Wu1,
                       const float* __restrict__ Wu2, const float* __restrict__ Wu3,
                       const float* __restrict__ W0, const float* __restrict__ Wo,
                       short* __restrict__ Wp, short* __restrict__ W0p,
                       short* __restrict__ WoP)
{
    const int b = blockIdx.x;
    const int t = threadIdx.x;
    if (b < 264) {
        __shared__ float Ld[64][66];
        const int mat = b >> 3, w = b & 7;
        const float* src;
        if (mat < 3) src = (mat == 0 ? W1 : (mat == 1 ? W2 : W3));
        else {
            int g = (mat - 3) / 10, d = (mat - 3) % 10;
            src = (g == 0 ? Wu1 : (g == 1 ? Wu2 : Wu3)) + (size_t)d * HIDN * HIDN;
        }
        short* dst = Wp + (size_t)mat * 262144 + w * 32768;
        for (int s = 0; s < 8; ++s) {
            __syncthreads();
            const int r4 = t >> 6, c = t & 63;
#pragma unroll
            for (int p = 0; p < 16; ++p) {
                int k = s * 64 + p * 4 + r4;
                Ld[p * 4 + r4][c] = src[(size_t)k * HIDN + w * 64 + c];
            }
            __syncthreads();
#pragma unroll
            for (int i = 0; i < 2; ++i) {
                int g = i * 256 + t;
                int ksl = g >> 7, of = (g >> 6) & 1, k8 = (g >> 5) & 1, c5 = g & 31;
                int kk = ksl * 16 + k8 * 8;
                unsigned pk[4];
#pragma unroll
                for (int j2 = 0; j2 < 4; ++j2) {
                    unsigned h0 = bfr_hi(Ld[kk + 2 * j2][of * 32 + c5]);
                    unsigned h1 = bfr_hi(Ld[kk + 2 * j2 + 1][of * 32 + c5]);
                    pk[j2] = (h0 >> 16) | (h1 & 0xffff0000u);
                }
                int ksg = s * 4 + ksl;
                *(uint4*)(dst + ksg * 1024 + of * 512 + k8 * 256 + c5 * 8) =
                    make_uint4(pk[0], pk[1], pk[2], pk[3]);
            }
        }
    } else if (b == 264) {
#pragma unroll
        for (int i = 0; i < 4; ++i) {
            int g = i * 256 + t;   // 1024 granules
            int w = g >> 7, of = (g >> 6) & 1, k8 = (g >> 5) & 1, c5 = g & 31;
            int col = w * 64 + of * 32 + c5;
            unsigned pk[4];
#pragma unroll
            for (int j2 = 0; j2 < 4; ++j2) {
                unsigned h0 = bfr_hi(W0[(size_t)(k8 * 8 + 2 * j2) * HIDN + col]);
                unsigned h1 = bfr_hi(W0[(size_t)(k8 * 8 + 2 * j2 + 1) * HIDN + col]);
                pk[j2] = (h0 >> 16) | (h1 & 0xffff0000u);
            }
            *(uint4*)(W0p + g * 8) = make_uint4(pk[0], pk[1], pk[2], pk[3]);
        }
    } else {
        const int dom = b - 265;
        const float* src = Wo + (size_t)dom * HIDN * STYLE;
        short* dst = WoP + (size_t)dom * 32768;
#pragma unroll
        for (int i = 0; i < 16; ++i) {
            int g = i * 256 + t;   // 4096 granules
            int w1 = g >> 11, ks = (g >> 6) & 31, k8 = (g >> 5) & 1, c5 = g & 31;
            int col = w1 * 32 + c5;
            int k0 = ks * 16 + k8 * 8;
            unsigned pk[4];
#pragma unroll
            for (int j2 = 0; j2 < 4; ++j2) {
                unsigned h0 = bfr_hi(src[(size_t)(k0 + 2 * j2) * STYLE + col]);
                unsigned h1 = bfr_hi(src[(size_t)(k0 + 2 * j2 + 1) * STYLE + col]);
                pk[j2] = (h0 >> 16) | (h1 & 0xffff0000u);
            }
            *(uint4*)(dst + g * 8) = make_uint4(pk[0], pk[1], pk[2], pk[3]);
        }
    }
}

// ---------------- fused persistent kernel ----------------
// 256 blocks x 512 threads (8 waves), block = 64 sorted rows.
// h in LDS, [octet o=k>>3][row][j=k&7] (no swizzle): idx = o*512 + row*8 + j.
// Operand-swapped MFMA: A = weights (m=outcol), B = activations (n=batchrow).
// Wave w owns outcols [64w,64w+64) (of=2); nf=2 batchrow groups of 32.
// Separate hi/lo accumulators (8 independent chains/wave).

__device__ __forceinline__ void pass512_impl(const short* sH, const short* sL,
                                             const short* pW, int lane,
                                             f32x16 ah[2][2], f32x16 al[2][2],
                                             int NFM, bool BLO);

template<int NFM, bool BLO>
__device__ __forceinline__ void pass512(const short* __restrict__ sH,
                                        const short* __restrict__ sL,
                                        const short* __restrict__ pW, int lane,
                                        f32x16 ah[2][2], f32x16 al[2][2])
{
#pragma unroll
    for (int of = 0; of < 2; ++of)
#pragma unroll
        for (int nf = 0; nf < 2; ++nf)
            if (NFM & (1 << nf)) {
#pragma unroll
                for (int e = 0; e < 16; ++e) ah[of][nf][e] = 0.f;
                if (BLO)
#pragma unroll
                    for (int e = 0; e < 16; ++e) al[of][nf][e] = 0.f;
            }
    const short* pWl = pW + lane * 8;
    const int rb = (lane & 31) * 8;
    const int lh = lane >> 5;
    bf16x8 wbuf[2][2];
    wbuf[0][0] = *(const bf16x8*)(pWl);
    wbuf[0][1] = *(const bf16x8*)(pWl + 512);
    wbuf[1][0] = *(const bf16x8*)(pWl + 1024);
    wbuf[1][1] = *(const bf16x8*)(pWl + 1536);
#pragma unroll
    for (int ks = 0; ks < 32; ++ks) {
        bf16x8 w0 = wbuf[ks & 1][0], w1 = wbuf[ks & 1][1];
        if (ks < 30) {
            wbuf[ks & 1][0] = *(const bf16x8*)(pWl + (ks + 2) * 1024);
            wbuf[ks & 1][1] = *(const bf16x8*)(pWl + (ks + 2) * 1024 + 512);
        }
        const int base = (2 * ks + lh) * 512 + rb;
#pragma unroll
        for (int nf = 0; nf < 2; ++nf) {
            if (!(NFM & (1 << nf))) continue;
            bf16x8 bh = *(const bf16x8*)(sH + base + nf * 256);
            ah[0][nf] = MFMA(w0, bh, ah[0][nf], 0, 0, 0);
            ah[1][nf] = MFMA(w1, bh, ah[1][nf], 0, 0, 0);
            if (BLO) {
                bf16x8 bl = *(const bf16x8*)(sL + base + nf * 256);
                al[0][nf] = MFMA(w0, bl, al[0][nf], 0, 0, 0);
                al[1][nf] = MFMA(w1, bl, al[1][nf], 0, 0, 0);
            }
        }
    }
}

// epilogue: merge accs + bias (+ReLU), pack bf16 hi(/lo), write h rows [rlo,rhi)
template<bool BLO, bool WLO, bool RELU>
__device__ __forceinline__ void epi512(short* __restrict__ sH, short* __restrict__ sL,
                                       f32x16 ah[2][2], f32x16 al[2][2],
                                       const float* __restrict__ bias,
                                       int w, int lane, int rlo, int rhi)
{
    const int lh = lane >> 5;
#pragma unroll
    for (int nf = 0; nf < 2; ++nf) {
        const int row = nf * 32 + (lane & 31);
        const bool pred = (row >= rlo && row < rhi);
#pragma unroll
        for (int of = 0; of < 2; ++of) {
#pragma unroll
            for (int q = 0; q < 4; ++q) {
                const float4 bv = *(const float4*)&bias[w * 64 + of * 32 + q * 8 + lh * 4];
                float v[4];
#pragma unroll
                for (int j = 0; j < 4; ++j) {
                    float x = ah[of][nf][q * 4 + j];
                    if (BLO) x += al[of][nf][q * 4 + j];
                    x += (&bv.x)[j];
                    if (RELU) x = fmaxf(x, 0.f);
                    v[j] = x;
                }
                unsigned h0 = cvtpk(v[0], v[1]);
                unsigned h1 = cvtpk(v[2], v[3]);
                const int idx = (w * 8 + of * 4 + q) * 512 + row * 8 + lh * 4;
                if (pred) *(uint2*)(sH + idx) = make_uint2(h0, h1);
                if (WLO) {
                    float l0 = v[0] - __uint_as_float(h0 << 16);
                    float l1 = v[1] - __uint_as_float(h0 & 0xffff0000u);
                    float l2 = v[2] - __uint_as_float(h1 << 16);
                    float l3 = v[3] - __uint_as_float(h1 & 0xffff0000u);
                    unsigned g0 = cvtpk(l0, l1);
                    unsigned g1 = cvtpk(l2, l3);
                    if (pred) *(uint2*)(sL + idx) = make_uint2(g0, g1);
                }
            }
        }
    }
}

__global__ __launch_bounds__(512, 2)
void k_fused(const float* __restrict__ z, const int* __restrict__ rowidx,
             const int* __restrict__ offsets,
             const short* __restrict__ Wp, const short* __restrict__ W0p,
             const short* __restrict__ WoP,
             const float* __restrict__ b0, const float* __restrict__ b1,
             const float* __restrict__ b2, const float* __restrict__ b3,
             const float* __restrict__ bu1, const float* __restrict__ bu2,
             const float* __restrict__ bu3, const float* __restrict__ bo,
             float* __restrict__ out)
{
    __shared__ short sH[32768];   // 64 KiB  (h hi)
    __shared__ short sL[32768];   // 64 KiB  (h lo; valid from layer-3 output on)
    __shared__ int soff[NDOM + 1];

    // XCD-chunked bijective swizzle: neighbors share a domain -> L2 reuse
    const int win = (blockIdx.x & 7) * 32 + (blockIdx.x >> 3);
    const int row0 = win * 64;
    const int tid = threadIdx.x;
    const int lane = tid & 63;
    const int w = tid >> 6;
    const int lh = lane >> 5;

    if (tid < NDOM + 1) soff[tid] = offsets[tid];

    f32x16 ah[2][2], al[2][2];

    // ---- layer 0: z (K=16) -> h (hi-only out; z itself split hi/lo) ----
    {
#pragma unroll
        for (int a = 0; a < 2; ++a)
#pragma unroll
            for (int b = 0; b < 2; ++b)
#pragma unroll
                for (int e = 0; e < 16; ++e) { ah[a][b][e] = 0.f; al[a][b][e] = 0.f; }
        const short* pw0 = W0p + w * 1024 + lane * 8;
        bf16x8 w0 = *(const bf16x8*)(pw0);
        bf16x8 w1 = *(const bf16x8*)(pw0 + 512);
#pragma unroll
        for (int nf = 0; nf < 2; ++nf) {
            int r = nf * 32 + (lane & 31);
            int src = rowidx[row0 + r];
            const float* zp = z + (size_t)src * 16 + lh * 8;
            float4 f0 = *(const float4*)zp;
            float4 f1 = *(const float4*)(zp + 4);
            uint4 h, l;
            cvhalf2(f0, f1, h, l);
            bf16x8 zh = *(bf16x8*)&h;
            bf16x8 zl = *(bf16x8*)&l;
            ah[0][nf] = MFMA(w0, zh, ah[0][nf], 0, 0, 0);
            ah[1][nf] = MFMA(w1, zh, ah[1][nf], 0, 0, 0);
            al[0][nf] = MFMA(w0, zl, al[0][nf], 0, 0, 0);
            al[1][nf] = MFMA(w1, zl, al[1][nf], 0, 0, 0);
        }
        epi512<true, false, true>(sH, sL, ah, al, b0, w, lane, 0, 64);
        __syncthreads();
    }

    // ---- trunk layers 1-3 (h hi-only inputs; layer 3 writes hi+lo) ----
#pragma unroll 1
    for (int m = 0; m < 3; ++m) {
        const float* bp = (m == 0) ? b1 : (m == 1) ? b2 : b3;
        pass512<3, false>(sH, sL, Wp + (size_t)m * 262144 + w * 32768, lane, ah, al);
        __syncthreads();
        if (m < 2) epi512<false, false, true>(sH, sL, ah, al, bp, w, lane, 0, 64);
        else       epi512<false, true,  true>(sH, sL, ah, al, bp, w, lane, 0, 64);
        __syncthreads();
    }

    // ---- head layers: per-domain, nf-granular (32-row groups) ----
#pragma unroll 1
    for (int L = 0; L < 3; ++L) {
        const short* WL_ = Wp + (size_t)(3 + L * 10) * 262144;
        const float* bL = (L == 0) ? bu1 : (L == 1) ? bu2 : bu3;
#pragma unroll 1
        for (int d = 0; d < NDOM; ++d) {
            int rlo = soff[d] - row0, rhi = soff[d + 1] - row0;
            rlo = rlo < 0 ? 0 : rlo;
            rhi = rhi > 64 ? 64 : rhi;
            if (rhi <= rlo) continue;
            const int nfm = (rlo < 32 ? 1 : 0) | (rhi > 32 ? 2 : 0);
            const short* pw = WL_ + (size_t)d * 262144 + w * 32768;
            if (nfm == 3)      pass512<3, true>(sH, sL, pw, lane, ah, al);
            else if (nfm == 1) pass512<1, true>(sH, sL, pw, lane, ah, al);
            else               pass512<2, true>(sH, sL, pw, lane, ah, al);
            __syncthreads();
            epi512<true, true, true>(sH, sL, ah, al, bL + d * HIDN, w, lane, rlo, rhi);
            __syncthreads();
        }
    }

    // ---- final 512->64: 4 waves, wave task (of, nf); coalesced float4 out ----
    if (w < 4) {
        const int of = w & 1, nff = w >> 1;
        const int rbase = nff * 32;
        const int r = rbase + (lane & 31);
#pragma unroll 1
        for (int d = 0; d < NDOM; ++d) {
            int rlo = soff[d] - row0, rhi = soff[d + 1] - row0;
            rlo = rlo < 0 ? 0 : rlo;
            rhi = rhi > 64 ? 64 : rhi;
            if (rhi <= rlo) continue;
            if (rhi <= rbase || rlo >= rbase + 32) continue;
            f32x16 fh, fl;
#pragma unroll
            for (int e = 0; e < 16; ++e) { fh[e] = 0.f; fl[e] = 0.f; }
            const short* pw = WoP + (size_t)d * 32768 + of * 16384 + lane * 8;
            bf16x8 wb[2];
            wb[0] = *(const bf16x8*)(pw);
            wb[1] = *(const bf16x8*)(pw + 512);
#pragma unroll
            for (int ks = 0; ks < 32; ++ks) {
                bf16x8 wk = wb[ks & 1];
                if (ks < 30) wb[ks & 1] = *(const bf16x8*)(pw + (ks + 2) * 512);
                const int base = (2 * ks + lh) * 512 + (lane & 31) * 8 + nff * 256;
                bf16x8 bhv = *(const bf16x8*)(sH + base);
                bf16x8 blv = *(const bf16x8*)(sL + base);
                fh = MFMA(wk, bhv, fh, 0, 0, 0);
                fl = MFMA(wk, blv, fl, 0, 0, 0);
            }
            if (r >= rlo && r < rhi) {
                const int orow = rowidx[row0 + r];
                float* op = out + (size_t)orow * STYLE + of * 32 + lh * 4;
                const float* bop = bo + d * STYLE + of * 32 + lh * 4;
#pragma unroll
                for (int q = 0; q < 4; ++q) {
                    float4 v;
                    v.x = fh[q * 4 + 0] + fl[q * 4 + 0] + bop[q * 8 + 0];
                    v.y = fh[q * 4 + 1] + fl[q * 4 + 1] + bop[q * 8 + 1];
                    v.z = fh[q * 4 + 2] + fl[q * 4 + 2] + bop[q * 8 + 2];
                    v.w = fh[q * 4 + 3] + fl[q * 4 + 3] + bop[q * 8 + 3];
                    *(float4*)(op + q * 8) = v;
                }
            }
        }
    }
}

// ---------------- launch ----------------

extern "C" void kernel_launch(void* const* d_in, const int* in_sizes, int n_in,
                              void* d_out, int out_size, void* d_ws, size_t ws_size,
                              hipStream_t stream) {
    const float* z   = (const float*)d_in[0];
    const int*   y   = (const int*)d_in[1];
    const float* W0  = (const float*)d_in[2];
    const float* b0  = (const float*)d_in[3];
    const float* W1  = (const float*)d_in[4];
    const float* b1  = (const float*)d_in[5];
    const float* W2  = (const float*)d_in[6];
    const float* b2  = (const float*)d_in[7];
    const float* W3  = (const float*)d_in[8];
    const float* b3  = (const float*)d_in[9];
    const float* Wu1 = (const float*)d_in[10];
    const float* bu1 = (const float*)d_in[11];
    const float* Wu2 = (const float*)d_in[12];
    const float* bu2 = (const float*)d_in[13];
    const float* Wu3 = (const float*)d_in[14];
    const float* bu3 = (const float*)d_in[15];
    const float* Wo  = (const float*)d_in[16];
    const float* bo  = (const float*)d_in[17];
    float* out = (float*)d_out;

    short* Wp   = (short*)d_ws;                      // 33 * 262144 shorts (16.5 MB)
    short* W0p  = Wp + (size_t)33 * 262144;          // 8192 shorts
    short* WoP  = W0p + 8192;                        // 10 * 32768 shorts
    int* rowidx  = (int*)(WoP + (size_t)10 * 32768); // NB ints
    int* offsets = rowidx + NB;                      // NDOM+1
    int* cursors = offsets + NDOM + 1;               // NDOM

    k_buckets<<<1, 1024, 0, stream>>>(y, offsets, cursors);
    k_scatter<<<NB / 256, 256, 0, stream>>>(y, offsets, cursors, rowidx);
    k_prep<<<275, 256, 0, stream>>>(W1, W2, W3, Wu1, Wu2, Wu3, W0, Wo, Wp, W0p, WoP);
    k_fused<<<NWIN, 512, 0, stream>>>(z, rowidx, offsets, Wp, W0p, WoP,
                                      b0, b1, b2, b3, bu1, bu2, bu3, bo, out);
}